// Round 1
// baseline (838.890 us; speedup 1.0000x reference)
//
#include <hip/hip_runtime.h>

#define LAYERS 2
#define DIM 1024
#define HEADS 16
#define HD 64
#define BATCH 2
#define SEQ 1024
#define ROWS (BATCH * SEQ) /* 2048 */
#define FFN (4 * DIM)      /* 4096 */
#define VOCAB 32000

typedef unsigned short u16;
typedef short vshort8 __attribute__((ext_vector_type(8)));
typedef float f32x4 __attribute__((ext_vector_type(4)));

__device__ __forceinline__ u16 f2bf(float f) {
  union { float f; unsigned u; } x{f};
  unsigned r = (x.u + 0x7fffu + ((x.u >> 16) & 1u)) >> 16;
  return (u16)r;
}

// async global->LDS, 16B per lane. LDS dest = wave-uniform base + lane*16.
__device__ __forceinline__ void gll16(const void* g, u16* l) {
  __builtin_amdgcn_global_load_lds(
      (const __attribute__((address_space(1))) void*)g,
      (__attribute__((address_space(3))) void*)l, 16, 0, 0);
}

// ---------------- transpose f32 [R,C] -> bf16 [C,R] ----------------
__global__ __launch_bounds__(256) void transpose_f32_bf16(
    const float* __restrict__ src, u16* __restrict__ dst, int R, int C) {
  __shared__ float tile[32][33];
  int c0 = blockIdx.x * 32, r0 = blockIdx.y * 32;
  int tx = threadIdx.x, ty = threadIdx.y;  // (32,8)
#pragma unroll
  for (int i = 0; i < 4; i++)
    tile[ty + i * 8][tx] = src[(size_t)(r0 + ty + i * 8) * C + c0 + tx];
  __syncthreads();
#pragma unroll
  for (int i = 0; i < 4; i++)
    dst[(size_t)(c0 + ty + i * 8) * R + r0 + tx] = f2bf(tile[tx][ty + i * 8]);
}

// ---------------- embedding gather ----------------
__global__ __launch_bounds__(256) void embed_gather(
    const int* __restrict__ ids, const float* __restrict__ emb,
    float* __restrict__ x) {
  int row = blockIdx.x;
  int id = ids[row];
  const float4* s = (const float4*)(emb + (size_t)id * DIM);
  float4* d = (float4*)(x + (size_t)row * DIM);
  d[threadIdx.x] = s[threadIdx.x];
}

// ---------------- rmsnorm: f32 in -> bf16 out ----------------
__global__ __launch_bounds__(256) void rmsnorm_kernel(
    const float* __restrict__ x, const float* __restrict__ g,
    u16* __restrict__ out) {
  int row = blockIdx.x;
  int t = threadIdx.x;
  const float4* xr = (const float4*)(x + (size_t)row * DIM);
  float4 v = xr[t];
  float ss = v.x * v.x + v.y * v.y + v.z * v.z + v.w * v.w;
  for (int off = 32; off > 0; off >>= 1) ss += __shfl_down(ss, off);
  __shared__ float part[4];
  if ((t & 63) == 0) part[t >> 6] = ss;
  __syncthreads();
  float tot = part[0] + part[1] + part[2] + part[3];
  float r = rsqrtf(tot / (float)DIM + 1e-6f);
  float4 gv = ((const float4*)g)[t];
  ushort4 o;
  o.x = f2bf(v.x * r * gv.x);
  o.y = f2bf(v.y * r * gv.y);
  o.z = f2bf(v.z * r * gv.z);
  o.w = f2bf(v.w * r * gv.w);
  *(ushort4*)(out + (size_t)row * DIM + t * 4) = o;
}

// ---------------- GEMM: C[M,N] = A[M,K](bf16) * Wt[N,K](bf16) + bias ----------------
// BN=128, BK=64, 256 threads (4 waves, 2x2). Swizzled LDS (slot ^= row&7) via
// pre-swizzled global source feeding global_load_lds (linear LDS dest).
template <int BM, int OUTBF, int SILU, int RES>
__global__ __launch_bounds__(256) void gemm_kernel(
    const u16* __restrict__ A, const u16* __restrict__ Wt,
    const float* __restrict__ bias, const float* __restrict__ res,
    void* __restrict__ outv, int M, int N, int K) {
  constexpr int BN = 128, BK = 64;
  constexpr int MT = BM / 32;  // M fragments per wave
  constexpr int NT = 4;        // N fragments per wave (64/16)
  __shared__ u16 As[BM * BK];
  __shared__ u16 Bs[BN * BK];
  int m0 = blockIdx.y * BM, n0 = blockIdx.x * BN;
  int tid = threadIdx.x;
  int wave = tid >> 6, lane = tid & 63;
  int wr = wave >> 1, wc = wave & 1;
  int r16 = lane & 15, g4 = lane >> 4;
  int lrow = lane >> 3;  // 0..7 row within 8-row segment
  int lslot = lane & 7;  // physical 16B slot within 128B row
  constexpr int SEGA = BM / 8, SEGB = BN / 8;

  f32x4 acc[MT][NT] = {};

  for (int k0 = 0; k0 < K; k0 += BK) {
    __syncthreads();
#pragma unroll
    for (int i = 0; i < SEGA / 4; i++) {
      int s = wave * (SEGA / 4) + i;
      int row = s * 8 + lrow;
      int klog = (lslot ^ (row & 7)) * 8;
      gll16(A + (size_t)(m0 + row) * K + k0 + klog, &As[s * 512 + lane * 8]);
    }
#pragma unroll
    for (int i = 0; i < SEGB / 4; i++) {
      int s = wave * (SEGB / 4) + i;
      int row = s * 8 + lrow;
      int klog = (lslot ^ (row & 7)) * 8;
      gll16(Wt + (size_t)(n0 + row) * K + k0 + klog, &Bs[s * 512 + lane * 8]);
    }
    __syncthreads();
#pragma unroll
    for (int kk = 0; kk < 2; kk++) {
      vshort8 af[MT], bf[NT];
#pragma unroll
      for (int m = 0; m < MT; m++) {
        int r = wr * (BM / 2) + m * 16 + r16;
        int slot = (kk * 4 + g4) ^ (r & 7);
        af[m] = *(const vshort8*)&As[r * 64 + slot * 8];
      }
#pragma unroll
      for (int n = 0; n < NT; n++) {
        int c = wc * 64 + n * 16 + r16;
        int slot = (kk * 4 + g4) ^ (c & 7);
        bf[n] = *(const vshort8*)&Bs[c * 64 + slot * 8];
      }
#pragma unroll
      for (int m = 0; m < MT; m++)
#pragma unroll
        for (int n = 0; n < NT; n++)
          acc[m][n] = __builtin_amdgcn_mfma_f32_16x16x32_bf16(af[m], bf[n],
                                                              acc[m][n], 0, 0, 0);
    }
  }

#pragma unroll
  for (int m = 0; m < MT; m++) {
    int rowb = m0 + wr * (BM / 2) + m * 16 + g4 * 4;
#pragma unroll
    for (int n = 0; n < NT; n++) {
      int col = n0 + wc * 64 + n * 16 + r16;
      float b = bias[col];
#pragma unroll
      for (int j = 0; j < 4; j++) {
        int row = rowb + j;
        float v = acc[m][n][j] + b;
        if (SILU) v = v / (1.f + __expf(-v));
        if (RES) v += res[(size_t)row * N + col];
        if (OUTBF)
          ((u16*)outv)[(size_t)row * N + col] = f2bf(v);
        else
          ((float*)outv)[(size_t)row * N + col] = v;
      }
    }
  }
}

// ---------------- v [B,S,H*HD](bf16) -> vt [B,H,HD,S](bf16) ----------------
__global__ __launch_bounds__(256) void vtrans_kernel(const u16* __restrict__ v,
                                                     u16* __restrict__ vt) {
  __shared__ u16 tile[32][33];
  int s0 = blockIdx.x * 32;
  int d0 = blockIdx.y * 32;
  int bh = blockIdx.z;
  int b = bh >> 4, h = bh & 15;
  int tx = threadIdx.x, ty = threadIdx.y;
#pragma unroll
  for (int i = 0; i < 4; i++)
    tile[ty + i * 8][tx] =
        v[(size_t)(b * SEQ + s0 + ty + i * 8) * DIM + h * HD + d0 + tx];
  __syncthreads();
#pragma unroll
  for (int i = 0; i < 4; i++)
    vt[((size_t)bh * HD + d0 + ty + i * 8) * SEQ + s0 + tx] = tile[tx][ty + i * 8];
}

// ---------------- flash attention ----------------
// grid (S/16, B*HEADS), 1 wave. q,k bf16 [B,S,DIM]; vt bf16 [B,H,HD,S]; o bf16.
__global__ __launch_bounds__(64) void attn_kernel(const u16* __restrict__ q,
                                                  const u16* __restrict__ k,
                                                  const u16* __restrict__ vt,
                                                  u16* __restrict__ o) {
  int qt = blockIdx.x;
  int bh = blockIdx.y;
  int b = bh >> 4, h = bh & 15;
  int lane = threadIdx.x;
  int r16 = lane & 15, g4 = lane >> 4;
  int q0 = qt * 16;
  __shared__ u16 pl[16 * 32];

  const u16* qrow = q + ((size_t)(b * SEQ) + q0 + r16) * DIM + h * HD;
  vshort8 aq0 = *(const vshort8*)(qrow + g4 * 8);
  vshort8 aq1 = *(const vshort8*)(qrow + 32 + g4 * 8);

  float mrun[4], lrun[4];
  f32x4 accO[4];
#pragma unroll
  for (int j = 0; j < 4; j++) { mrun[j] = -1e30f; lrun[j] = 0.f; }
#pragma unroll
  for (int d = 0; d < 4; d++) accO[d] = f32x4{0.f, 0.f, 0.f, 0.f};

  int nkv = (q0 >> 5) + 1;
  for (int kt = 0; kt < nkv; kt++) {
    int kv0 = kt * 32;
    const u16* krow0 = k + ((size_t)(b * SEQ) + kv0 + r16) * DIM + h * HD;
    const u16* krow1 = krow0 + 16 * DIM;
    vshort8 bk00 = *(const vshort8*)(krow0 + g4 * 8);
    vshort8 bk01 = *(const vshort8*)(krow0 + 32 + g4 * 8);
    vshort8 bk10 = *(const vshort8*)(krow1 + g4 * 8);
    vshort8 bk11 = *(const vshort8*)(krow1 + 32 + g4 * 8);
    f32x4 s0 = {}, s1 = {};
    s0 = __builtin_amdgcn_mfma_f32_16x16x32_bf16(aq0, bk00, s0, 0, 0, 0);
    s0 = __builtin_amdgcn_mfma_f32_16x16x32_bf16(aq1, bk01, s0, 0, 0, 0);
    s1 = __builtin_amdgcn_mfma_f32_16x16x32_bf16(aq0, bk10, s1, 0, 0, 0);
    s1 = __builtin_amdgcn_mfma_f32_16x16x32_bf16(aq1, bk11, s1, 0, 0, 0);

#pragma unroll
    for (int j = 0; j < 4; j++) {
      int qg = q0 + g4 * 4 + j;
      float x0 = s0[j] * 0.125f;
      float x1 = s1[j] * 0.125f;
      if (kv0 + r16 > qg) x0 = -1e30f;
      if (kv0 + 16 + r16 > qg) x1 = -1e30f;
      float mx = fmaxf(x0, x1);
#pragma unroll
      for (int mm = 1; mm < 16; mm <<= 1) mx = fmaxf(mx, __shfl_xor(mx, mm));
      float mnew = fmaxf(mrun[j], mx);
      float alpha = __expf(mrun[j] - mnew);
      float p0 = __expf(x0 - mnew);
      float p1 = __expf(x1 - mnew);
      float rs = p0 + p1;
#pragma unroll
      for (int mm = 1; mm < 16; mm <<= 1) rs += __shfl_xor(rs, mm);
      lrun[j] = lrun[j] * alpha + rs;
      mrun[j] = mnew;
#pragma unroll
      for (int d = 0; d < 4; d++) accO[d][j] *= alpha;
      pl[(g4 * 4 + j) * 32 + r16] = f2bf(p0);
      pl[(g4 * 4 + j) * 32 + 16 + r16] = f2bf(p1);
    }
    __syncthreads();
    vshort8 ap = *(const vshort8*)&pl[r16 * 32 + g4 * 8];
    const u16* vrow = vt + (size_t)bh * HD * SEQ + kv0 + g4 * 8;
#pragma unroll
    for (int d = 0; d < 4; d++) {
      vshort8 bv = *(const vshort8*)(vrow + (size_t)(d * 16 + r16) * SEQ);
      accO[d] = __builtin_amdgcn_mfma_f32_16x16x32_bf16(ap, bv, accO[d], 0, 0, 0);
    }
    __syncthreads();
  }

#pragma unroll
  for (int j = 0; j < 4; j++) {
    float inv = 1.f / lrun[j];
    int row = q0 + g4 * 4 + j;
#pragma unroll
    for (int d = 0; d < 4; d++)
      o[((size_t)(b * SEQ) + row) * DIM + h * HD + d * 16 + r16] =
          f2bf(accO[d][j] * inv);
  }
}

// ---------------- host ----------------
extern "C" void kernel_launch(void* const* d_in, const int* in_sizes, int n_in,
                              void* d_out, int out_size, void* d_ws,
                              size_t ws_size, hipStream_t stream) {
  const int* ids = (const int*)d_in[0];
  const float* emb = (const float*)d_in[1];
  const float* g1 = (const float*)d_in[2];
  const float* wq = (const float*)d_in[3];
  const float* bq = (const float*)d_in[4];
  const float* wk = (const float*)d_in[5];
  const float* bk = (const float*)d_in[6];
  const float* wv = (const float*)d_in[7];
  const float* bv = (const float*)d_in[8];
  const float* wo = (const float*)d_in[9];
  const float* bo = (const float*)d_in[10];
  const float* g2 = (const float*)d_in[11];
  const float* w1 = (const float*)d_in[12];
  const float* b1 = (const float*)d_in[13];
  const float* w2 = (const float*)d_in[14];
  const float* b2 = (const float*)d_in[15];
  const float* gf = (const float*)d_in[16];
  const float* head_w = (const float*)d_in[17];
  const float* head_b = (const float*)d_in[18];
  float* out = (float*)d_out;

  char* ws = (char*)d_ws;
  size_t off = 0;
  auto alloc = [&](size_t bytes) -> char* {
    char* p = ws + off;
    off += (bytes + 255) & ~(size_t)255;
    return p;
  };
  u16* wqT = (u16*)alloc((size_t)LAYERS * DIM * DIM * 2);
  u16* wkT = (u16*)alloc((size_t)LAYERS * DIM * DIM * 2);
  u16* wvT = (u16*)alloc((size_t)LAYERS * DIM * DIM * 2);
  u16* woT = (u16*)alloc((size_t)LAYERS * DIM * DIM * 2);
  u16* w1T = (u16*)alloc((size_t)LAYERS * DIM * FFN * 2);
  u16* w2T = (u16*)alloc((size_t)LAYERS * DIM * FFN * 2);
  u16* headT = (u16*)alloc((size_t)VOCAB * DIM * 2);
  float* x = (float*)alloc((size_t)ROWS * DIM * 4);
  u16* h = (u16*)alloc((size_t)ROWS * DIM * 2);
  u16* qb = (u16*)alloc((size_t)ROWS * DIM * 2);
  u16* kb = (u16*)alloc((size_t)ROWS * DIM * 2);
  u16* vb = (u16*)alloc((size_t)ROWS * DIM * 2);
  u16* vtb = (u16*)alloc((size_t)ROWS * DIM * 2);
  u16* ob = (u16*)alloc((size_t)ROWS * DIM * 2);
  u16* tb = (u16*)alloc((size_t)ROWS * FFN * 2);
  if (off > ws_size) return;  // workspace too small: bail (will fail validation)

  dim3 tb32(32, 8);
  // weight transposes (every launch; deterministic)
  for (int l = 0; l < LAYERS; l++) {
    transpose_f32_bf16<<<dim3(DIM / 32, DIM / 32), tb32, 0, stream>>>(
        wq + (size_t)l * DIM * DIM, wqT + (size_t)l * DIM * DIM, DIM, DIM);
    transpose_f32_bf16<<<dim3(DIM / 32, DIM / 32), tb32, 0, stream>>>(
        wk + (size_t)l * DIM * DIM, wkT + (size_t)l * DIM * DIM, DIM, DIM);
    transpose_f32_bf16<<<dim3(DIM / 32, DIM / 32), tb32, 0, stream>>>(
        wv + (size_t)l * DIM * DIM, wvT + (size_t)l * DIM * DIM, DIM, DIM);
    transpose_f32_bf16<<<dim3(DIM / 32, DIM / 32), tb32, 0, stream>>>(
        wo + (size_t)l * DIM * DIM, woT + (size_t)l * DIM * DIM, DIM, DIM);
    transpose_f32_bf16<<<dim3(FFN / 32, DIM / 32), tb32, 0, stream>>>(
        w1 + (size_t)l * DIM * FFN, w1T + (size_t)l * DIM * FFN, DIM, FFN);
    transpose_f32_bf16<<<dim3(DIM / 32, FFN / 32), tb32, 0, stream>>>(
        w2 + (size_t)l * DIM * FFN, w2T + (size_t)l * DIM * FFN, FFN, DIM);
  }
  transpose_f32_bf16<<<dim3(VOCAB / 32, DIM / 32), tb32, 0, stream>>>(
      head_w, headT, DIM, VOCAB);

  embed_gather<<<ROWS, 256, 0, stream>>>(ids, emb, x);

  for (int l = 0; l < LAYERS; l++) {
    rmsnorm_kernel<<<ROWS, 256, 0, stream>>>(x, g1 + (size_t)l * DIM, h);
    gemm_kernel<64, 1, 0, 0><<<dim3(DIM / 128, ROWS / 64), 256, 0, stream>>>(
        h, wqT + (size_t)l * DIM * DIM, bq + (size_t)l * DIM, nullptr, qb,
        ROWS, DIM, DIM);
    gemm_kernel<64, 1, 0, 0><<<dim3(DIM / 128, ROWS / 64), 256, 0, stream>>>(
        h, wkT + (size_t)l * DIM * DIM, bk + (size_t)l * DIM, nullptr, kb,
        ROWS, DIM, DIM);
    gemm_kernel<64, 1, 0, 0><<<dim3(DIM / 128, ROWS / 64), 256, 0, stream>>>(
        h, wvT + (size_t)l * DIM * DIM, bv + (size_t)l * DIM, nullptr, vb,
        ROWS, DIM, DIM);
    vtrans_kernel<<<dim3(SEQ / 32, 2, BATCH * HEADS), tb32, 0, stream>>>(vb, vtb);
    attn_kernel<<<dim3(SEQ / 16, BATCH * HEADS), 64, 0, stream>>>(qb, kb, vtb, ob);
    gemm_kernel<64, 0, 0, 1><<<dim3(DIM / 128, ROWS / 64), 256, 0, stream>>>(
        ob, woT + (size_t)l * DIM * DIM, bo + (size_t)l * DIM, x, x,
        ROWS, DIM, DIM);
    rmsnorm_kernel<<<ROWS, 256, 0, stream>>>(x, g2 + (size_t)l * DIM, h);
    gemm_kernel<128, 1, 1, 0><<<dim3(FFN / 128, ROWS / 128), 256, 0, stream>>>(
        h, w1T + (size_t)l * DIM * FFN, b1 + (size_t)l * FFN, nullptr, tb,
        ROWS, FFN, DIM);
    gemm_kernel<64, 0, 0, 1><<<dim3(DIM / 128, ROWS / 64), 256, 0, stream>>>(
        tb, w2T + (size_t)l * DIM * FFN, b2 + (size_t)l * DIM, x, x,
        ROWS, DIM, FFN);
  }
  rmsnorm_kernel<<<ROWS, 256, 0, stream>>>(x, gf, h);
  gemm_kernel<128, 0, 0, 0><<<dim3(VOCAB / 128, ROWS / 128), 256, 0, stream>>>(
      h, headT, head_b, nullptr, out, ROWS, VOCAB, DIM);
}

// Round 2
// 744.738 us; speedup vs baseline: 1.1264x; 1.1264x over previous
//
#include <hip/hip_runtime.h>

#define LAYERS 2
#define DIM 1024
#define HEADS 16
#define HD 64
#define BATCH 2
#define SEQ 1024
#define ROWS (BATCH * SEQ) /* 2048 */
#define FFN (4 * DIM)      /* 4096 */
#define VOCAB 32000
#define QKVN (3 * DIM) /* 3072 */

typedef unsigned short u16;
typedef short vshort8 __attribute__((ext_vector_type(8)));
typedef float f32x4 __attribute__((ext_vector_type(4)));

__device__ __forceinline__ u16 f2bf(float f) {
  union { float f; unsigned u; } x{f};
  unsigned r = (x.u + 0x7fffu + ((x.u >> 16) & 1u)) >> 16;
  return (u16)r;
}

// async global->LDS, 16B per lane. LDS dest = wave-uniform base + lane*16.
__device__ __forceinline__ void gll16(const void* g, u16* l) {
  __builtin_amdgcn_global_load_lds(
      (const __attribute__((address_space(1))) void*)g,
      (__attribute__((address_space(3))) void*)l, 16, 0, 0);
}

// bijective XCD swizzle (m204): hardware orig%8 -> contiguous logical chunks
__device__ __forceinline__ int xcd_swizzle(int orig, int nwg) {
  int q = nwg >> 3, r = nwg & 7;
  int xcd = orig & 7;
  int base = (xcd < r) ? xcd * (q + 1) : r * (q + 1) + (xcd - r) * q;
  return base + (orig >> 3);
}

// ---------------- transpose f32 [R,C] -> bf16 [C,R] ----------------
__global__ __launch_bounds__(256) void transpose_f32_bf16(
    const float* __restrict__ src, u16* __restrict__ dst, int R, int C) {
  __shared__ float tile[32][33];
  int c0 = blockIdx.x * 32, r0 = blockIdx.y * 32;
  int tx = threadIdx.x, ty = threadIdx.y;  // (32,8)
#pragma unroll
  for (int i = 0; i < 4; i++)
    tile[ty + i * 8][tx] = src[(size_t)(r0 + ty + i * 8) * C + c0 + tx];
  __syncthreads();
#pragma unroll
  for (int i = 0; i < 4; i++)
    dst[(size_t)(c0 + ty + i * 8) * R + r0 + tx] = f2bf(tile[tx][ty + i * 8]);
}

// ---------------- pack q/k/v biases into one [3072] vector ----------------
__global__ __launch_bounds__(256) void pack_qkv_bias(
    const float* __restrict__ bq, const float* __restrict__ bk,
    const float* __restrict__ bv, float* __restrict__ o) {
  int t = blockIdx.x * 256 + threadIdx.x;
  if (t < DIM) o[t] = bq[t];
  else if (t < 2 * DIM) o[t] = bk[t - DIM];
  else if (t < 3 * DIM) o[t] = bv[t - 2 * DIM];
}

// ---------------- embedding gather ----------------
__global__ __launch_bounds__(256) void embed_gather(
    const int* __restrict__ ids, const float* __restrict__ emb,
    float* __restrict__ x) {
  int row = blockIdx.x;
  int id = ids[row];
  const float4* s = (const float4*)(emb + (size_t)id * DIM);
  float4* d = (float4*)(x + (size_t)row * DIM);
  d[threadIdx.x] = s[threadIdx.x];
}

// ---------------- rmsnorm: f32 in -> bf16 out ----------------
__global__ __launch_bounds__(256) void rmsnorm_kernel(
    const float* __restrict__ x, const float* __restrict__ g,
    u16* __restrict__ out) {
  int row = blockIdx.x;
  int t = threadIdx.x;
  const float4* xr = (const float4*)(x + (size_t)row * DIM);
  float4 v = xr[t];
  float ss = v.x * v.x + v.y * v.y + v.z * v.z + v.w * v.w;
  for (int off = 32; off > 0; off >>= 1) ss += __shfl_down(ss, off);
  __shared__ float part[4];
  if ((t & 63) == 0) part[t >> 6] = ss;
  __syncthreads();
  float tot = part[0] + part[1] + part[2] + part[3];
  float r = rsqrtf(tot / (float)DIM + 1e-6f);
  float4 gv = ((const float4*)g)[t];
  ushort4 o;
  o.x = f2bf(v.x * r * gv.x);
  o.y = f2bf(v.y * r * gv.y);
  o.z = f2bf(v.z * r * gv.z);
  o.w = f2bf(v.w * r * gv.w);
  *(ushort4*)(out + (size_t)row * DIM + t * 4) = o;
}

// ---------------- GEMM: C[M,N] = A[M,K](bf16) * Wt[N,K](bf16) + bias ----------------
// BN=128, BK=64, 256 threads (4 waves, 2x2). 1-D grid + XCD-bijective swizzle.
// MFAST=1: m-tile fastest (for B >> A); MFAST=0: n-tile fastest (A >= B).
template <int BM, int OUTBF, int SILU, int RES, int MFAST>
__global__ __launch_bounds__(256) void gemm_kernel(
    const u16* __restrict__ A, const u16* __restrict__ Wt,
    const float* __restrict__ bias, const float* __restrict__ res,
    void* __restrict__ outv, int M, int N, int K) {
  constexpr int BN = 128, BK = 64;
  constexpr int MT = BM / 32;  // M fragments per wave
  constexpr int NT = 4;        // N fragments per wave (64/16)
  __shared__ u16 As[BM * BK];
  __shared__ u16 Bs[BN * BK];
  int nm = M / BM, nn = N / BN;
  int wg = xcd_swizzle(blockIdx.x, nm * nn);
  int mi, ni;
  if (MFAST) { mi = wg % nm; ni = wg / nm; }
  else       { ni = wg % nn; mi = wg / nn; }
  int m0 = mi * BM, n0 = ni * BN;
  int tid = threadIdx.x;
  int wave = tid >> 6, lane = tid & 63;
  int wr = wave >> 1, wc = wave & 1;
  int r16 = lane & 15, g4 = lane >> 4;
  int lrow = lane >> 3;  // 0..7 row within 8-row segment
  int lslot = lane & 7;  // physical 16B slot within 128B row
  constexpr int SEGA = BM / 8, SEGB = BN / 8;

  f32x4 acc[MT][NT] = {};

  for (int k0 = 0; k0 < K; k0 += BK) {
    __syncthreads();
#pragma unroll
    for (int i = 0; i < SEGA / 4; i++) {
      int s = wave * (SEGA / 4) + i;
      int row = s * 8 + lrow;
      int klog = (lslot ^ (row & 7)) * 8;
      gll16(A + (size_t)(m0 + row) * K + k0 + klog, &As[s * 512 + lane * 8]);
    }
#pragma unroll
    for (int i = 0; i < SEGB / 4; i++) {
      int s = wave * (SEGB / 4) + i;
      int row = s * 8 + lrow;
      int klog = (lslot ^ (row & 7)) * 8;
      gll16(Wt + (size_t)(n0 + row) * K + k0 + klog, &Bs[s * 512 + lane * 8]);
    }
    __syncthreads();
#pragma unroll
    for (int kk = 0; kk < 2; kk++) {
      vshort8 af[MT], bf[NT];
#pragma unroll
      for (int m = 0; m < MT; m++) {
        int r = wr * (BM / 2) + m * 16 + r16;
        int slot = (kk * 4 + g4) ^ (r & 7);
        af[m] = *(const vshort8*)&As[r * 64 + slot * 8];
      }
#pragma unroll
      for (int n = 0; n < NT; n++) {
        int c = wc * 64 + n * 16 + r16;
        int slot = (kk * 4 + g4) ^ (c & 7);
        bf[n] = *(const vshort8*)&Bs[c * 64 + slot * 8];
      }
#pragma unroll
      for (int m = 0; m < MT; m++)
#pragma unroll
        for (int n = 0; n < NT; n++)
          acc[m][n] = __builtin_amdgcn_mfma_f32_16x16x32_bf16(af[m], bf[n],
                                                              acc[m][n], 0, 0, 0);
    }
  }

#pragma unroll
  for (int m = 0; m < MT; m++) {
    int rowb = m0 + wr * (BM / 2) + m * 16 + g4 * 4;
#pragma unroll
    for (int n = 0; n < NT; n++) {
      int col = n0 + wc * 64 + n * 16 + r16;
      float b = bias[col];
#pragma unroll
      for (int j = 0; j < 4; j++) {
        int row = rowb + j;
        float v = acc[m][n][j] + b;
        if (SILU) v = v / (1.f + __expf(-v));
        if (RES) v += res[(size_t)row * N + col];
        if (OUTBF)
          ((u16*)outv)[(size_t)row * N + col] = f2bf(v);
        else
          ((float*)outv)[(size_t)row * N + col] = v;
      }
    }
  }
}

// ---------------- v slice of qkv [B,S,3072] -> vt [B,H,HD,S](bf16) ----------------
__global__ __launch_bounds__(256) void vtrans_kernel(const u16* __restrict__ qkv,
                                                     u16* __restrict__ vt) {
  __shared__ u16 tile[32][33];
  int s0 = blockIdx.x * 32;
  int d0 = blockIdx.y * 32;
  int bh = blockIdx.z;
  int b = bh >> 4, h = bh & 15;
  int tx = threadIdx.x, ty = threadIdx.y;
#pragma unroll
  for (int i = 0; i < 4; i++)
    tile[ty + i * 8][tx] =
        qkv[(size_t)(b * SEQ + s0 + ty + i * 8) * QKVN + 2 * DIM + h * HD + d0 + tx];
  __syncthreads();
#pragma unroll
  for (int i = 0; i < 4; i++)
    vt[((size_t)bh * HD + d0 + ty + i * 8) * SEQ + s0 + tx] = tile[tx][ty + i * 8];
}

// ---------------- flash attention ----------------
// grid (S/16, B*HEADS), 1 wave. qkv bf16 [B,S,3072] (q at +0, k at +DIM);
// vt bf16 [B,H,HD,S]; o bf16 [B,S,DIM].
__global__ __launch_bounds__(64) void attn_kernel(const u16* __restrict__ qkv,
                                                  const u16* __restrict__ vt,
                                                  u16* __restrict__ o) {
  int qt = blockIdx.x;
  int bh = blockIdx.y;
  int b = bh >> 4, h = bh & 15;
  int lane = threadIdx.x;
  int r16 = lane & 15, g4 = lane >> 4;
  int q0 = qt * 16;
  __shared__ u16 pl[16 * 32];

  const u16* qrow = qkv + ((size_t)(b * SEQ) + q0 + r16) * QKVN + h * HD;
  vshort8 aq0 = *(const vshort8*)(qrow + g4 * 8);
  vshort8 aq1 = *(const vshort8*)(qrow + 32 + g4 * 8);

  float mrun[4], lrun[4];
  f32x4 accO[4];
#pragma unroll
  for (int j = 0; j < 4; j++) { mrun[j] = -1e30f; lrun[j] = 0.f; }
#pragma unroll
  for (int d = 0; d < 4; d++) accO[d] = f32x4{0.f, 0.f, 0.f, 0.f};

  int nkv = (q0 >> 5) + 1;
  for (int kt = 0; kt < nkv; kt++) {
    int kv0 = kt * 32;
    const u16* krow0 = qkv + ((size_t)(b * SEQ) + kv0 + r16) * QKVN + DIM + h * HD;
    const u16* krow1 = krow0 + (size_t)16 * QKVN;
    vshort8 bk00 = *(const vshort8*)(krow0 + g4 * 8);
    vshort8 bk01 = *(const vshort8*)(krow0 + 32 + g4 * 8);
    vshort8 bk10 = *(const vshort8*)(krow1 + g4 * 8);
    vshort8 bk11 = *(const vshort8*)(krow1 + 32 + g4 * 8);
    f32x4 s0 = {}, s1 = {};
    s0 = __builtin_amdgcn_mfma_f32_16x16x32_bf16(aq0, bk00, s0, 0, 0, 0);
    s0 = __builtin_amdgcn_mfma_f32_16x16x32_bf16(aq1, bk01, s0, 0, 0, 0);
    s1 = __builtin_amdgcn_mfma_f32_16x16x32_bf16(aq0, bk10, s1, 0, 0, 0);
    s1 = __builtin_amdgcn_mfma_f32_16x16x32_bf16(aq1, bk11, s1, 0, 0, 0);

#pragma unroll
    for (int j = 0; j < 4; j++) {
      int qg = q0 + g4 * 4 + j;
      float x0 = s0[j] * 0.125f;
      float x1 = s1[j] * 0.125f;
      if (kv0 + r16 > qg) x0 = -1e30f;
      if (kv0 + 16 + r16 > qg) x1 = -1e30f;
      float mx = fmaxf(x0, x1);
#pragma unroll
      for (int mm = 1; mm < 16; mm <<= 1) mx = fmaxf(mx, __shfl_xor(mx, mm));
      float mnew = fmaxf(mrun[j], mx);
      float alpha = __expf(mrun[j] - mnew);
      float p0 = __expf(x0 - mnew);
      float p1 = __expf(x1 - mnew);
      float rs = p0 + p1;
#pragma unroll
      for (int mm = 1; mm < 16; mm <<= 1) rs += __shfl_xor(rs, mm);
      lrun[j] = lrun[j] * alpha + rs;
      mrun[j] = mnew;
#pragma unroll
      for (int d = 0; d < 4; d++) accO[d][j] *= alpha;
      pl[(g4 * 4 + j) * 32 + r16] = f2bf(p0);
      pl[(g4 * 4 + j) * 32 + 16 + r16] = f2bf(p1);
    }
    __syncthreads();
    vshort8 ap = *(const vshort8*)&pl[r16 * 32 + g4 * 8];
    const u16* vrow = vt + (size_t)bh * HD * SEQ + kv0 + g4 * 8;
#pragma unroll
    for (int d = 0; d < 4; d++) {
      vshort8 bv = *(const vshort8*)(vrow + (size_t)(d * 16 + r16) * SEQ);
      accO[d] = __builtin_amdgcn_mfma_f32_16x16x32_bf16(ap, bv, accO[d], 0, 0, 0);
    }
    __syncthreads();
  }

#pragma unroll
  for (int j = 0; j < 4; j++) {
    float inv = 1.f / lrun[j];
    int row = q0 + g4 * 4 + j;
#pragma unroll
    for (int d = 0; d < 4; d++)
      o[((size_t)(b * SEQ) + row) * DIM + h * HD + d * 16 + r16] =
          f2bf(accO[d][j] * inv);
  }
}

// ---------------- host ----------------
extern "C" void kernel_launch(void* const* d_in, const int* in_sizes, int n_in,
                              void* d_out, int out_size, void* d_ws,
                              size_t ws_size, hipStream_t stream) {
  const int* ids = (const int*)d_in[0];
  const float* emb = (const float*)d_in[1];
  const float* g1 = (const float*)d_in[2];
  const float* wq = (const float*)d_in[3];
  const float* bq = (const float*)d_in[4];
  const float* wk = (const float*)d_in[5];
  const float* bk = (const float*)d_in[6];
  const float* wv = (const float*)d_in[7];
  const float* bv = (const float*)d_in[8];
  const float* wo = (const float*)d_in[9];
  const float* bo = (const float*)d_in[10];
  const float* g2 = (const float*)d_in[11];
  const float* w1 = (const float*)d_in[12];
  const float* b1 = (const float*)d_in[13];
  const float* w2 = (const float*)d_in[14];
  const float* b2 = (const float*)d_in[15];
  const float* gf = (const float*)d_in[16];
  const float* head_w = (const float*)d_in[17];
  const float* head_b = (const float*)d_in[18];
  float* out = (float*)d_out;

  char* ws = (char*)d_ws;
  size_t off = 0;
  auto alloc = [&](size_t bytes) -> char* {
    char* p = ws + off;
    off += (bytes + 255) & ~(size_t)255;
    return p;
  };
  u16* wqkvT = (u16*)alloc((size_t)LAYERS * QKVN * DIM * 2);  // [l][3072][1024]
  u16* woT = (u16*)alloc((size_t)LAYERS * DIM * DIM * 2);
  u16* w1T = (u16*)alloc((size_t)LAYERS * DIM * FFN * 2);
  u16* w2T = (u16*)alloc((size_t)LAYERS * DIM * FFN * 2);
  u16* headT = (u16*)alloc((size_t)VOCAB * DIM * 2);
  float* bqkv = (float*)alloc((size_t)LAYERS * QKVN * 4);
  float* x = (float*)alloc((size_t)ROWS * DIM * 4);
  u16* h = (u16*)alloc((size_t)ROWS * DIM * 2);
  u16* qkvb = (u16*)alloc((size_t)ROWS * QKVN * 2);
  u16* vtb = (u16*)alloc((size_t)ROWS * DIM * 2);
  u16* ob = (u16*)alloc((size_t)ROWS * DIM * 2);
  u16* tb = (u16*)alloc((size_t)ROWS * FFN * 2);
  if (off > ws_size) return;  // workspace too small: bail

  dim3 tb32(32, 8);
  for (int l = 0; l < LAYERS; l++) {
    u16* base = wqkvT + (size_t)l * QKVN * DIM;
    transpose_f32_bf16<<<dim3(DIM / 32, DIM / 32), tb32, 0, stream>>>(
        wq + (size_t)l * DIM * DIM, base, DIM, DIM);
    transpose_f32_bf16<<<dim3(DIM / 32, DIM / 32), tb32, 0, stream>>>(
        wk + (size_t)l * DIM * DIM, base + (size_t)DIM * DIM, DIM, DIM);
    transpose_f32_bf16<<<dim3(DIM / 32, DIM / 32), tb32, 0, stream>>>(
        wv + (size_t)l * DIM * DIM, base + (size_t)2 * DIM * DIM, DIM, DIM);
    transpose_f32_bf16<<<dim3(DIM / 32, DIM / 32), tb32, 0, stream>>>(
        wo + (size_t)l * DIM * DIM, woT + (size_t)l * DIM * DIM, DIM, DIM);
    transpose_f32_bf16<<<dim3(FFN / 32, DIM / 32), tb32, 0, stream>>>(
        w1 + (size_t)l * DIM * FFN, w1T + (size_t)l * DIM * FFN, DIM, FFN);
    transpose_f32_bf16<<<dim3(DIM / 32, FFN / 32), tb32, 0, stream>>>(
        w2 + (size_t)l * DIM * FFN, w2T + (size_t)l * DIM * FFN, FFN, DIM);
    pack_qkv_bias<<<QKVN / 256, 256, 0, stream>>>(
        bq + (size_t)l * DIM, bk + (size_t)l * DIM, bv + (size_t)l * DIM,
        bqkv + (size_t)l * QKVN);
  }
  transpose_f32_bf16<<<dim3(VOCAB / 32, DIM / 32), tb32, 0, stream>>>(
      head_w, headT, DIM, VOCAB);

  embed_gather<<<ROWS, 256, 0, stream>>>(ids, emb, x);

  for (int l = 0; l < LAYERS; l++) {
    rmsnorm_kernel<<<ROWS, 256, 0, stream>>>(x, g1 + (size_t)l * DIM, h);
    // fused QKV: [2048,3072] = h @ WqkvT
    gemm_kernel<128, 1, 0, 0, 1>
        <<<(ROWS / 128) * (QKVN / 128), 256, 0, stream>>>(
            h, wqkvT + (size_t)l * QKVN * DIM, bqkv + (size_t)l * QKVN,
            nullptr, qkvb, ROWS, QKVN, DIM);
    vtrans_kernel<<<dim3(SEQ / 32, 2, BATCH * HEADS), tb32, 0, stream>>>(qkvb, vtb);
    attn_kernel<<<dim3(SEQ / 16, BATCH * HEADS), 64, 0, stream>>>(qkvb, vtb, ob);
    gemm_kernel<64, 0, 0, 1, 0>
        <<<(ROWS / 64) * (DIM / 128), 256, 0, stream>>>(
            ob, woT + (size_t)l * DIM * DIM, bo + (size_t)l * DIM, x, x,
            ROWS, DIM, DIM);
    rmsnorm_kernel<<<ROWS, 256, 0, stream>>>(x, g2 + (size_t)l * DIM, h);
    gemm_kernel<128, 1, 1, 0, 1>
        <<<(ROWS / 128) * (FFN / 128), 256, 0, stream>>>(
            h, w1T + (size_t)l * DIM * FFN, b1 + (size_t)l * FFN, nullptr, tb,
            ROWS, FFN, DIM);
    gemm_kernel<64, 0, 0, 1, 0>
        <<<(ROWS / 64) * (DIM / 128), 256, 0, stream>>>(
            tb, w2T + (size_t)l * DIM * FFN, b2 + (size_t)l * DIM, x, x,
            ROWS, DIM, FFN);
  }
  rmsnorm_kernel<<<ROWS, 256, 0, stream>>>(x, gf, h);
  gemm_kernel<128, 0, 0, 0, 1>
      <<<(ROWS / 128) * (VOCAB / 128), 256, 0, stream>>>(
          h, headT, head_b, nullptr, out, ROWS, VOCAB, DIM);
}

// Round 3
// 723.259 us; speedup vs baseline: 1.1599x; 1.0297x over previous
//
#include <hip/hip_runtime.h>

#define LAYERS 2
#define DIM 1024
#define HEADS 16
#define HD 64
#define BATCH 2
#define SEQ 1024
#define ROWS (BATCH * SEQ) /* 2048 */
#define FFN (4 * DIM)      /* 4096 */
#define VOCAB 32000
#define QKVN (3 * DIM) /* 3072 */

typedef unsigned short u16;
typedef short vshort8 __attribute__((ext_vector_type(8)));
typedef float f32x4 __attribute__((ext_vector_type(4)));

#define VMCNT(n) asm volatile("s_waitcnt vmcnt(" #n ")" ::: "memory")

__device__ __forceinline__ u16 f2bf(float f) {
  union { float f; unsigned u; } x{f};
  unsigned r = (x.u + 0x7fffu + ((x.u >> 16) & 1u)) >> 16;
  return (u16)r;
}

// async global->LDS, 16B per lane. LDS dest = wave-uniform base + lane*16.
__device__ __forceinline__ void gll16(const void* g, u16* l) {
  __builtin_amdgcn_global_load_lds(
      (const __attribute__((address_space(1))) void*)g,
      (__attribute__((address_space(3))) void*)l, 16, 0, 0);
}

// bijective XCD swizzle (m204)
__device__ __forceinline__ int xcd_swizzle(int orig, int nwg) {
  int q = nwg >> 3, r = nwg & 7;
  int xcd = orig & 7;
  int base = (xcd < r) ? xcd * (q + 1) : r * (q + 1) + (xcd - r) * q;
  return base + (orig >> 3);
}

// ---------------- transpose f32 [R,C] -> bf16 [C,R] ----------------
__global__ __launch_bounds__(256) void transpose_f32_bf16(
    const float* __restrict__ src, u16* __restrict__ dst, int R, int C) {
  __shared__ float tile[32][33];
  int c0 = blockIdx.x * 32, r0 = blockIdx.y * 32;
  int tx = threadIdx.x, ty = threadIdx.y;  // (32,8)
#pragma unroll
  for (int i = 0; i < 4; i++)
    tile[ty + i * 8][tx] = src[(size_t)(r0 + ty + i * 8) * C + c0 + tx];
  __syncthreads();
#pragma unroll
  for (int i = 0; i < 4; i++)
    dst[(size_t)(c0 + ty + i * 8) * R + r0 + tx] = f2bf(tile[tx][ty + i * 8]);
}

// ---------------- pack q/k/v biases into one [3072] vector ----------------
__global__ __launch_bounds__(256) void pack_qkv_bias(
    const float* __restrict__ bq, const float* __restrict__ bk,
    const float* __restrict__ bv, float* __restrict__ o) {
  int t = blockIdx.x * 256 + threadIdx.x;
  if (t < DIM) o[t] = bq[t];
  else if (t < 2 * DIM) o[t] = bk[t - DIM];
  else if (t < 3 * DIM) o[t] = bv[t - 2 * DIM];
}

// ---------------- embedding gather ----------------
__global__ __launch_bounds__(256) void embed_gather(
    const int* __restrict__ ids, const float* __restrict__ emb,
    float* __restrict__ x) {
  int row = blockIdx.x;
  int id = ids[row];
  const float4* s = (const float4*)(emb + (size_t)id * DIM);
  float4* d = (float4*)(x + (size_t)row * DIM);
  d[threadIdx.x] = s[threadIdx.x];
}

// ---------------- rmsnorm: f32 in -> bf16 out ----------------
__global__ __launch_bounds__(256) void rmsnorm_kernel(
    const float* __restrict__ x, const float* __restrict__ g,
    u16* __restrict__ out) {
  int row = blockIdx.x;
  int t = threadIdx.x;
  const float4* xr = (const float4*)(x + (size_t)row * DIM);
  float4 v = xr[t];
  float ss = v.x * v.x + v.y * v.y + v.z * v.z + v.w * v.w;
  for (int off = 32; off > 0; off >>= 1) ss += __shfl_down(ss, off);
  __shared__ float part[4];
  if ((t & 63) == 0) part[t >> 6] = ss;
  __syncthreads();
  float tot = part[0] + part[1] + part[2] + part[3];
  float r = rsqrtf(tot / (float)DIM + 1e-6f);
  float4 gv = ((const float4*)g)[t];
  ushort4 o;
  o.x = f2bf(v.x * r * gv.x);
  o.y = f2bf(v.y * r * gv.y);
  o.z = f2bf(v.z * r * gv.z);
  o.w = f2bf(v.w * r * gv.w);
  *(ushort4*)(out + (size_t)row * DIM + t * 4) = o;
}

// ---------------- GEMM 128-tile (layer GEMMs) ----------------
template <int BM, int OUTBF, int SILU, int RES, int MFAST>
__global__ __launch_bounds__(256) void gemm_kernel(
    const u16* __restrict__ A, const u16* __restrict__ Wt,
    const float* __restrict__ bias, const float* __restrict__ res,
    void* __restrict__ outv, int M, int N, int K) {
  constexpr int BN = 128, BK = 64;
  constexpr int MT = BM / 32;
  constexpr int NT = 4;
  __shared__ u16 As[BM * BK];
  __shared__ u16 Bs[BN * BK];
  int nm = M / BM, nn = N / BN;
  int wg = xcd_swizzle(blockIdx.x, nm * nn);
  int mi, ni;
  if (MFAST) { mi = wg % nm; ni = wg / nm; }
  else       { ni = wg % nn; mi = wg / nn; }
  int m0 = mi * BM, n0 = ni * BN;
  int tid = threadIdx.x;
  int wave = tid >> 6, lane = tid & 63;
  int wr = wave >> 1, wc = wave & 1;
  int r16 = lane & 15, g4 = lane >> 4;
  int lrow = lane >> 3;
  int lslot = lane & 7;
  constexpr int SEGA = BM / 8, SEGB = BN / 8;

  f32x4 acc[MT][NT] = {};

  for (int k0 = 0; k0 < K; k0 += BK) {
    __syncthreads();
#pragma unroll
    for (int i = 0; i < SEGA / 4; i++) {
      int s = wave * (SEGA / 4) + i;
      int row = s * 8 + lrow;
      int klog = (lslot ^ (row & 7)) * 8;
      gll16(A + (size_t)(m0 + row) * K + k0 + klog, &As[s * 512 + lane * 8]);
    }
#pragma unroll
    for (int i = 0; i < SEGB / 4; i++) {
      int s = wave * (SEGB / 4) + i;
      int row = s * 8 + lrow;
      int klog = (lslot ^ (row & 7)) * 8;
      gll16(Wt + (size_t)(n0 + row) * K + k0 + klog, &Bs[s * 512 + lane * 8]);
    }
    __syncthreads();
#pragma unroll
    for (int kk = 0; kk < 2; kk++) {
      vshort8 af[MT], bf[NT];
#pragma unroll
      for (int m = 0; m < MT; m++) {
        int r = wr * (BM / 2) + m * 16 + r16;
        int slot = (kk * 4 + g4) ^ (r & 7);
        af[m] = *(const vshort8*)&As[r * 64 + slot * 8];
      }
#pragma unroll
      for (int n = 0; n < NT; n++) {
        int c = wc * 64 + n * 16 + r16;
        int slot = (kk * 4 + g4) ^ (c & 7);
        bf[n] = *(const vshort8*)&Bs[c * 64 + slot * 8];
      }
#pragma unroll
      for (int m = 0; m < MT; m++)
#pragma unroll
        for (int n = 0; n < NT; n++)
          acc[m][n] = __builtin_amdgcn_mfma_f32_16x16x32_bf16(af[m], bf[n],
                                                              acc[m][n], 0, 0, 0);
    }
  }

#pragma unroll
  for (int m = 0; m < MT; m++) {
    int rowb = m0 + wr * (BM / 2) + m * 16 + g4 * 4;
#pragma unroll
    for (int n = 0; n < NT; n++) {
      int col = n0 + wc * 64 + n * 16 + r16;
      float b = bias[col];
#pragma unroll
      for (int j = 0; j < 4; j++) {
        int row = rowb + j;
        float v = acc[m][n][j] + b;
        if (SILU) v = v / (1.f + __expf(-v));
        if (RES) v += res[(size_t)row * N + col];
        if (OUTBF)
          ((u16*)outv)[(size_t)row * N + col] = f2bf(v);
        else
          ((float*)outv)[(size_t)row * N + col] = v;
      }
    }
  }
}

// ---------------- GEMM 256x256, 8-phase pipelined (head GEMM) ----------------
// 512 thr = 8 waves (2M x 4N); BK=64; LDS 128KB double-buffered; counted vmcnt.
__global__ __launch_bounds__(512, 2) void gemm256_kernel(
    const u16* __restrict__ A, const u16* __restrict__ Wt,
    const float* __restrict__ bias, float* __restrict__ out,
    int M, int N, int K) {
  __shared__ u16 As[2][256 * 64];
  __shared__ u16 Bs[2][256 * 64];
  int nm = M >> 8, nn = N >> 8;
  int wg = xcd_swizzle(blockIdx.x, nm * nn);
  int mi = wg % nm, ni = wg / nm;  // m-fastest: B-panel reuse within XCD
  int m0 = mi << 8, n0 = ni << 8;
  int tid = threadIdx.x, w = tid >> 6, lane = tid & 63;
  int wr = w >> 2, wc = w & 3;
  int r16 = lane & 15, g4 = lane >> 4;
  int srow8 = lane >> 3, sslot = lane & 7;
  int NT = K >> 6;

  f32x4 acc[8][4] = {};

  auto stageA = [&](int buf, int t, int hb, int j) {
    int chunk = j * 8 + w;                   // 0..15
    int row = hb * 128 + chunk * 8 + srow8;  // 0..255
    int slot = sslot ^ (row & 7);
    gll16(A + (size_t)(m0 + row) * K + t * 64 + slot * 8,
          &As[buf][hb * 8192 + chunk * 512 + lane * 8]);
  };
  auto stageB = [&](int buf, int t, int hb, int j) {
    int chunk = j * 8 + w;
    int row = hb * 128 + chunk * 8 + srow8;
    int slot = sslot ^ (row & 7);
    gll16(Wt + (size_t)(n0 + row) * K + t * 64 + slot * 8,
          &Bs[buf][hb * 8192 + chunk * 512 + lane * 8]);
  };
  auto readA = [&](int buf, int mf, int kk) -> vshort8 {
    int row = mf * 32 + wr * 16 + r16;
    int slot = (kk * 4 + g4) ^ (row & 7);
    return *(const vshort8*)&As[buf][row * 64 + slot * 8];
  };
  auto readB = [&](int buf, int nf, int kk) -> vshort8 {
    int row = nf * 64 + wc * 16 + r16;
    int slot = (kk * 4 + g4) ^ (row & 7);
    return *(const vshort8*)&Bs[buf][row * 64 + slot * 8];
  };

  // prologue: stage tile 0 (batch {A0,B0} then batch {B1,A1})
  stageA(0, 0, 0, 0); stageA(0, 0, 0, 1); stageB(0, 0, 0, 0); stageB(0, 0, 0, 1);
  stageB(0, 0, 1, 0); stageB(0, 0, 1, 1); stageA(0, 0, 1, 0); stageA(0, 0, 1, 1);
  VMCNT(4);
  __builtin_amdgcn_s_barrier();

  vshort8 af[4][2], bf0[2][2], bf1[2][2];

  for (int t = 0; t < NT; t++) {
    int cur = t & 1, nxt = cur ^ 1;
    bool hn = (t + 1 < NT);
    // ---- phase 0: quadrant (A-half0, B-half0) ----
#pragma unroll
    for (int m = 0; m < 4; m++)
#pragma unroll
      for (int kk = 0; kk < 2; kk++) af[m][kk] = readA(cur, m, kk);
#pragma unroll
    for (int n = 0; n < 2; n++)
#pragma unroll
      for (int kk = 0; kk < 2; kk++) bf0[n][kk] = readB(cur, n, kk);
    if (hn) { stageA(nxt, t + 1, 0, 0); stageA(nxt, t + 1, 0, 1);
              stageB(nxt, t + 1, 0, 0); stageB(nxt, t + 1, 0, 1); }
    __builtin_amdgcn_s_barrier();
    __builtin_amdgcn_s_setprio(1);
#pragma unroll
    for (int m = 0; m < 4; m++)
#pragma unroll
      for (int n = 0; n < 2; n++)
#pragma unroll
        for (int kk = 0; kk < 2; kk++)
          acc[m][n] = __builtin_amdgcn_mfma_f32_16x16x32_bf16(
              af[m][kk], bf0[n][kk], acc[m][n], 0, 0, 0);
    __builtin_amdgcn_s_setprio(0);
    if (hn) VMCNT(4); else VMCNT(0);
    __builtin_amdgcn_s_barrier();
    // ---- phase 1: (A-half0, B-half1) ----
#pragma unroll
    for (int n = 0; n < 2; n++)
#pragma unroll
      for (int kk = 0; kk < 2; kk++) bf1[n][kk] = readB(cur, 2 + n, kk);
    if (hn) { stageB(nxt, t + 1, 1, 0); stageB(nxt, t + 1, 1, 1);
              stageA(nxt, t + 1, 1, 0); stageA(nxt, t + 1, 1, 1); }
    __builtin_amdgcn_s_barrier();
    __builtin_amdgcn_s_setprio(1);
#pragma unroll
    for (int m = 0; m < 4; m++)
#pragma unroll
      for (int n = 0; n < 2; n++)
#pragma unroll
        for (int kk = 0; kk < 2; kk++)
          acc[m][n + 2] = __builtin_amdgcn_mfma_f32_16x16x32_bf16(
              af[m][kk], bf1[n][kk], acc[m][n + 2], 0, 0, 0);
    __builtin_amdgcn_s_setprio(0);
    __builtin_amdgcn_s_barrier();
    // ---- phase 2: (A-half1, B-half1) ----
#pragma unroll
    for (int m = 0; m < 4; m++)
#pragma unroll
      for (int kk = 0; kk < 2; kk++) af[m][kk] = readA(cur, 4 + m, kk);
    __builtin_amdgcn_s_barrier();
    __builtin_amdgcn_s_setprio(1);
#pragma unroll
    for (int m = 0; m < 4; m++)
#pragma unroll
      for (int n = 0; n < 2; n++)
#pragma unroll
        for (int kk = 0; kk < 2; kk++)
          acc[m + 4][n + 2] = __builtin_amdgcn_mfma_f32_16x16x32_bf16(
              af[m][kk], bf1[n][kk], acc[m + 4][n + 2], 0, 0, 0);
    __builtin_amdgcn_s_setprio(0);
    __builtin_amdgcn_s_barrier();
    // ---- phase 3: (A-half1, B-half0) ----
#pragma unroll
    for (int n = 0; n < 2; n++)
#pragma unroll
      for (int kk = 0; kk < 2; kk++) bf0[n][kk] = readB(cur, n, kk);
    __builtin_amdgcn_s_barrier();
    __builtin_amdgcn_s_setprio(1);
#pragma unroll
    for (int m = 0; m < 4; m++)
#pragma unroll
      for (int n = 0; n < 2; n++)
#pragma unroll
        for (int kk = 0; kk < 2; kk++)
          acc[m + 4][n] = __builtin_amdgcn_mfma_f32_16x16x32_bf16(
              af[m][kk], bf0[n][kk], acc[m + 4][n], 0, 0, 0);
    __builtin_amdgcn_s_setprio(0);
    if (hn) VMCNT(4);
    __builtin_amdgcn_s_barrier();
  }

  // epilogue
#pragma unroll
  for (int mf = 0; mf < 8; mf++) {
    int rowb = m0 + mf * 32 + wr * 16 + g4 * 4;
#pragma unroll
    for (int nf = 0; nf < 4; nf++) {
      int col = n0 + nf * 64 + wc * 16 + r16;
      float b = bias[col];
#pragma unroll
      for (int j = 0; j < 4; j++)
        out[(size_t)(rowb + j) * N + col] = acc[mf][nf][j] + b;
    }
  }
}

// ---------------- V slice of qkv -> vt2 [bh][S/8][64][8] ----------------
__global__ __launch_bounds__(256) void vtrans_kernel(const u16* __restrict__ qkv,
                                                     u16* __restrict__ vt2) {
  __shared__ u16 tl[64][80];
  int s0 = blockIdx.x * 64;
  int bh = blockIdx.y;
  int b = bh >> 4, h = bh & 15;
  int tid = threadIdx.x;
#pragma unroll
  for (int c = 0; c < 2; c++) {
    int idx = tid + c * 256;
    int row = idx >> 3;
    int col8 = (idx & 7) * 8;
    *(vshort8*)&tl[row][col8] = *(const vshort8*)
        &qkv[(size_t)(b * SEQ + s0 + row) * QKVN + 2 * DIM + h * HD + col8];
  }
  __syncthreads();
#pragma unroll
  for (int c = 0; c < 2; c++) {
    int idx = tid + c * 256;
    int s8l = idx >> 6;  // 0..7
    int d = idx & 63;
    vshort8 v;
#pragma unroll
    for (int j = 0; j < 8; j++) v[j] = (short)tl[s8l * 8 + j][d];
    *(vshort8*)&vt2[(((size_t)bh * (SEQ / 8) + (s0 >> 3) + s8l) * 64 + d) * 8] = v;
  }
}

// ---------------- flash attention: 4-wave blocks, LDS-staged K ----------------
// grid (SEQ/64, B*HEADS), 256 thr. qkv bf16 [B,S,3072]; vt2 [bh][S/8][64][8].
__global__ __launch_bounds__(256) void attn_kernel(const u16* __restrict__ qkv,
                                                   const u16* __restrict__ vt2,
                                                   u16* __restrict__ o) {
  __shared__ u16 Ks[2][32 * 64];
  __shared__ u16 pl[4][16 * 40];  // stride 40: kills 8-way conflict on ap read
  int qblk = blockIdx.x, bh = blockIdx.y;
  int b = bh >> 4, h = bh & 15;
  int tid = threadIdx.x, w = tid >> 6, lane = tid & 63;
  int r16 = lane & 15, g4 = lane >> 4;
  int q0 = qblk * 64 + w * 16;

  const u16* qrow = qkv + ((size_t)(b * SEQ) + q0 + r16) * QKVN + h * HD;
  vshort8 aq0 = *(const vshort8*)(qrow + g4 * 8);
  vshort8 aq1 = *(const vshort8*)(qrow + 32 + g4 * 8);

  float mrun[4], lrun[4];
  f32x4 accO[4];
#pragma unroll
  for (int j = 0; j < 4; j++) { mrun[j] = -1e30f; lrun[j] = 0.f; }
#pragma unroll
  for (int d = 0; d < 4; d++) accO[d] = f32x4{0.f, 0.f, 0.f, 0.f};

  int nkvT = qblk * 2 + 2;
  auto stageK = [&](int buf, int kt) {
    int row = tid >> 3;  // 0..31
    int slot = (tid & 7) ^ (row & 7);
    gll16(qkv + ((size_t)(b * SEQ) + kt * 32 + row) * QKVN + DIM + h * HD + slot * 8,
          &Ks[buf][w * 512 + lane * 8]);
  };
  stageK(0, 0);
  __syncthreads();
  int buf = 0;
  for (int kt = 0; kt < nkvT; kt++) {
    int kv0 = kt * 32;
    if (kt + 1 < nkvT) stageK(buf ^ 1, kt + 1);
    if (kv0 <= q0 + 15) {  // wave-uniform causal skip
      int row0 = r16, row1 = 16 + r16;
      vshort8 bk00 = *(const vshort8*)&Ks[buf][row0 * 64 + ((0 + g4) ^ (row0 & 7)) * 8];
      vshort8 bk01 = *(const vshort8*)&Ks[buf][row0 * 64 + ((4 + g4) ^ (row0 & 7)) * 8];
      vshort8 bk10 = *(const vshort8*)&Ks[buf][row1 * 64 + ((0 + g4) ^ (row1 & 7)) * 8];
      vshort8 bk11 = *(const vshort8*)&Ks[buf][row1 * 64 + ((4 + g4) ^ (row1 & 7)) * 8];
      f32x4 s0 = {}, s1 = {};
      s0 = __builtin_amdgcn_mfma_f32_16x16x32_bf16(aq0, bk00, s0, 0, 0, 0);
      s0 = __builtin_amdgcn_mfma_f32_16x16x32_bf16(aq1, bk01, s0, 0, 0, 0);
      s1 = __builtin_amdgcn_mfma_f32_16x16x32_bf16(aq0, bk10, s1, 0, 0, 0);
      s1 = __builtin_amdgcn_mfma_f32_16x16x32_bf16(aq1, bk11, s1, 0, 0, 0);

#pragma unroll
      for (int j = 0; j < 4; j++) {
        int qg = q0 + g4 * 4 + j;
        float x0 = s0[j] * 0.125f;
        float x1 = s1[j] * 0.125f;
        if (kv0 + r16 > qg) x0 = -1e30f;
        if (kv0 + 16 + r16 > qg) x1 = -1e30f;
        float mx = fmaxf(x0, x1);
#pragma unroll
        for (int mm = 1; mm < 16; mm <<= 1) mx = fmaxf(mx, __shfl_xor(mx, mm));
        float mnew = fmaxf(mrun[j], mx);
        float alpha = __expf(mrun[j] - mnew);
        float p0 = __expf(x0 - mnew);
        float p1 = __expf(x1 - mnew);
        float rs = p0 + p1;
#pragma unroll
        for (int mm = 1; mm < 16; mm <<= 1) rs += __shfl_xor(rs, mm);
        lrun[j] = lrun[j] * alpha + rs;
        mrun[j] = mnew;
#pragma unroll
        for (int d = 0; d < 4; d++) accO[d][j] *= alpha;
        pl[w][(g4 * 4 + j) * 40 + r16] = f2bf(p0);
        pl[w][(g4 * 4 + j) * 40 + 16 + r16] = f2bf(p1);
      }
      // wave-local fence: P writes visible to this wave's reads
      asm volatile("s_waitcnt lgkmcnt(0)" ::: "memory");
      vshort8 ap = *(const vshort8*)&pl[w][r16 * 40 + g4 * 8];
      const u16* vbase = vt2 + (((size_t)bh * (SEQ / 8) + (kv0 >> 3) + g4) * 64) * 8;
#pragma unroll
      for (int d = 0; d < 4; d++) {
        vshort8 bv = *(const vshort8*)(vbase + (size_t)(d * 16 + r16) * 8);
        accO[d] = __builtin_amdgcn_mfma_f32_16x16x32_bf16(ap, bv, accO[d], 0, 0, 0);
      }
    }
    __syncthreads();  // drains gll (vmcnt0) -> next buf ready; separates reuse
    buf ^= 1;
  }

#pragma unroll
  for (int j = 0; j < 4; j++) {
    float inv = 1.f / lrun[j];
    int row = q0 + g4 * 4 + j;
#pragma unroll
    for (int d = 0; d < 4; d++)
      o[((size_t)(b * SEQ) + row) * DIM + h * HD + d * 16 + r16] =
          f2bf(accO[d][j] * inv);
  }
}

// ---------------- host ----------------
extern "C" void kernel_launch(void* const* d_in, const int* in_sizes, int n_in,
                              void* d_out, int out_size, void* d_ws,
                              size_t ws_size, hipStream_t stream) {
  const int* ids = (const int*)d_in[0];
  const float* emb = (const float*)d_in[1];
  const float* g1 = (const float*)d_in[2];
  const float* wq = (const float*)d_in[3];
  const float* bq = (const float*)d_in[4];
  const float* wk = (const float*)d_in[5];
  const float* bk = (const float*)d_in[6];
  const float* wv = (const float*)d_in[7];
  const float* bv = (const float*)d_in[8];
  const float* wo = (const float*)d_in[9];
  const float* bo = (const float*)d_in[10];
  const float* g2 = (const float*)d_in[11];
  const float* w1 = (const float*)d_in[12];
  const float* b1 = (const float*)d_in[13];
  const float* w2 = (const float*)d_in[14];
  const float* b2 = (const float*)d_in[15];
  const float* gf = (const float*)d_in[16];
  const float* head_w = (const float*)d_in[17];
  const float* head_b = (const float*)d_in[18];
  float* out = (float*)d_out;

  char* ws = (char*)d_ws;
  size_t off = 0;
  auto alloc = [&](size_t bytes) -> char* {
    char* p = ws + off;
    off += (bytes + 255) & ~(size_t)255;
    return p;
  };
  u16* wqkvT = (u16*)alloc((size_t)LAYERS * QKVN * DIM * 2);
  u16* woT = (u16*)alloc((size_t)LAYERS * DIM * DIM * 2);
  u16* w1T = (u16*)alloc((size_t)LAYERS * DIM * FFN * 2);
  u16* w2T = (u16*)alloc((size_t)LAYERS * DIM * FFN * 2);
  u16* headT = (u16*)alloc((size_t)VOCAB * DIM * 2);
  float* bqkv = (float*)alloc((size_t)LAYERS * QKVN * 4);
  float* x = (float*)alloc((size_t)ROWS * DIM * 4);
  u16* h = (u16*)alloc((size_t)ROWS * DIM * 2);
  u16* qkvb = (u16*)alloc((size_t)ROWS * QKVN * 2);
  u16* vtb = (u16*)alloc((size_t)ROWS * DIM * 2);
  u16* ob = (u16*)alloc((size_t)ROWS * DIM * 2);
  u16* tb = (u16*)alloc((size_t)ROWS * FFN * 2);
  if (off > ws_size) return;

  dim3 tb32(32, 8);
  for (int l = 0; l < LAYERS; l++) {
    u16* base = wqkvT + (size_t)l * QKVN * DIM;
    transpose_f32_bf16<<<dim3(DIM / 32, DIM / 32), tb32, 0, stream>>>(
        wq + (size_t)l * DIM * DIM, base, DIM, DIM);
    transpose_f32_bf16<<<dim3(DIM / 32, DIM / 32), tb32, 0, stream>>>(
        wk + (size_t)l * DIM * DIM, base + (size_t)DIM * DIM, DIM, DIM);
    transpose_f32_bf16<<<dim3(DIM / 32, DIM / 32), tb32, 0, stream>>>(
        wv + (size_t)l * DIM * DIM, base + (size_t)2 * DIM * DIM, DIM, DIM);
    transpose_f32_bf16<<<dim3(DIM / 32, DIM / 32), tb32, 0, stream>>>(
        wo + (size_t)l * DIM * DIM, woT + (size_t)l * DIM * DIM, DIM, DIM);
    transpose_f32_bf16<<<dim3(FFN / 32, DIM / 32), tb32, 0, stream>>>(
        w1 + (size_t)l * DIM * FFN, w1T + (size_t)l * DIM * FFN, DIM, FFN);
    transpose_f32_bf16<<<dim3(DIM / 32, FFN / 32), tb32, 0, stream>>>(
        w2 + (size_t)l * DIM * FFN, w2T + (size_t)l * DIM * FFN, FFN, DIM);
    pack_qkv_bias<<<QKVN / 256, 256, 0, stream>>>(
        bq + (size_t)l * DIM, bk + (size_t)l * DIM, bv + (size_t)l * DIM,
        bqkv + (size_t)l * QKVN);
  }
  transpose_f32_bf16<<<dim3(VOCAB / 32, DIM / 32), tb32, 0, stream>>>(
      head_w, headT, DIM, VOCAB);

  embed_gather<<<ROWS, 256, 0, stream>>>(ids, emb, x);

  for (int l = 0; l < LAYERS; l++) {
    rmsnorm_kernel<<<ROWS, 256, 0, stream>>>(x, g1 + (size_t)l * DIM, h);
    gemm_kernel<128, 1, 0, 0, 1>
        <<<(ROWS / 128) * (QKVN / 128), 256, 0, stream>>>(
            h, wqkvT + (size_t)l * QKVN * DIM, bqkv + (size_t)l * QKVN,
            nullptr, qkvb, ROWS, QKVN, DIM);
    vtrans_kernel<<<dim3(SEQ / 64, BATCH * HEADS), 256, 0, stream>>>(qkvb, vtb);
    attn_kernel<<<dim3(SEQ / 64, BATCH * HEADS), 256, 0, stream>>>(qkvb, vtb, ob);
    gemm_kernel<64, 0, 0, 1, 0>
        <<<(ROWS / 64) * (DIM / 128), 256, 0, stream>>>(
            ob, woT + (size_t)l * DIM * DIM, bo + (size_t)l * DIM, x, x,
            ROWS, DIM, DIM);
    rmsnorm_kernel<<<ROWS, 256, 0, stream>>>(x, g2 + (size_t)l * DIM, h);
    gemm_kernel<128, 1, 1, 0, 1>
        <<<(ROWS / 128) * (FFN / 128), 256, 0, stream>>>(
            h, w1T + (size_t)l * DIM * FFN, b1 + (size_t)l * FFN, nullptr, tb,
            ROWS, FFN, DIM);
    gemm_kernel<64, 0, 0, 1, 0>
        <<<(ROWS / 64) * (DIM / 128), 256, 0, stream>>>(
            tb, w2T + (size_t)l * DIM * FFN, b2 + (size_t)l * DIM, x, x,
            ROWS, DIM, FFN);
  }
  rmsnorm_kernel<<<ROWS, 256, 0, stream>>>(x, gf, h);
  gemm256_kernel<<<(ROWS / 256) * (VOCAB / 256), 512, 0, stream>>>(
      h, headT, head_b, out, ROWS, VOCAB, DIM);
}

// Round 4
// 670.929 us; speedup vs baseline: 1.2503x; 1.0780x over previous
//
#include <hip/hip_runtime.h>

#define LAYERS 2
#define DIM 1024
#define HEADS 16
#define HD 64
#define BATCH 2
#define SEQ 1024
#define ROWS (BATCH * SEQ) /* 2048 */
#define FFN (4 * DIM)      /* 4096 */
#define VOCAB 32000
#define QKVN (3 * DIM) /* 3072 */

typedef unsigned short u16;
typedef short vshort8 __attribute__((ext_vector_type(8)));
typedef float f32x4 __attribute__((ext_vector_type(4)));

#define VMCNT(n) asm volatile("s_waitcnt vmcnt(" #n ")" ::: "memory")

__device__ __forceinline__ u16 f2bf(float f) {
  union { float f; unsigned u; } x{f};
  unsigned r = (x.u + 0x7fffu + ((x.u >> 16) & 1u)) >> 16;
  return (u16)r;
}

__device__ __forceinline__ void gll16(const void* g, u16* l) {
  __builtin_amdgcn_global_load_lds(
      (const __attribute__((address_space(1))) void*)g,
      (__attribute__((address_space(3))) void*)l, 16, 0, 0);
}

// bijective XCD swizzle (m204)
__device__ __forceinline__ int xcd_swizzle(int orig, int nwg) {
  int q = nwg >> 3, r = nwg & 7;
  int xcd = orig & 7;
  int base = (xcd < r) ? xcd * (q + 1) : r * (q + 1) + (xcd - r) * q;
  return base + (orig >> 3);
}

// ---------------- transpose f32 [R,C] -> bf16 [C,R] ----------------
__global__ __launch_bounds__(256) void transpose_f32_bf16(
    const float* __restrict__ src, u16* __restrict__ dst, int R, int C) {
  __shared__ float tile[32][33];
  int c0 = blockIdx.x * 32, r0 = blockIdx.y * 32;
  int tx = threadIdx.x, ty = threadIdx.y;  // (32,8)
#pragma unroll
  for (int i = 0; i < 4; i++)
    tile[ty + i * 8][tx] = src[(size_t)(r0 + ty + i * 8) * C + c0 + tx];
  __syncthreads();
#pragma unroll
  for (int i = 0; i < 4; i++)
    dst[(size_t)(c0 + ty + i * 8) * R + r0 + tx] = f2bf(tile[tx][ty + i * 8]);
}

// ---------------- pack q/k/v biases into one [3072] vector ----------------
__global__ __launch_bounds__(256) void pack_qkv_bias(
    const float* __restrict__ bq, const float* __restrict__ bk,
    const float* __restrict__ bv, float* __restrict__ o) {
  int t = blockIdx.x * 256 + threadIdx.x;
  if (t < DIM) o[t] = bq[t];
  else if (t < 2 * DIM) o[t] = bk[t - DIM];
  else if (t < 3 * DIM) o[t] = bv[t - 2 * DIM];
}

// ---------------- embedding gather ----------------
__global__ __launch_bounds__(256) void embed_gather(
    const int* __restrict__ ids, const float* __restrict__ emb,
    float* __restrict__ x) {
  int row = blockIdx.x;
  int id = ids[row];
  const float4* s = (const float4*)(emb + (size_t)id * DIM);
  float4* d = (float4*)(x + (size_t)row * DIM);
  d[threadIdx.x] = s[threadIdx.x];
}

// ---------------- rmsnorm: f32 in -> bf16 out ----------------
__global__ __launch_bounds__(256) void rmsnorm_kernel(
    const float* __restrict__ x, const float* __restrict__ g,
    u16* __restrict__ out) {
  int row = blockIdx.x;
  int t = threadIdx.x;
  const float4* xr = (const float4*)(x + (size_t)row * DIM);
  float4 v = xr[t];
  float ss = v.x * v.x + v.y * v.y + v.z * v.z + v.w * v.w;
  for (int off = 32; off > 0; off >>= 1) ss += __shfl_down(ss, off);
  __shared__ float part[4];
  if ((t & 63) == 0) part[t >> 6] = ss;
  __syncthreads();
  float tot = part[0] + part[1] + part[2] + part[3];
  float r = rsqrtf(tot / (float)DIM + 1e-6f);
  float4 gv = ((const float4*)g)[t];
  ushort4 o;
  o.x = f2bf(v.x * r * gv.x);
  o.y = f2bf(v.y * r * gv.y);
  o.z = f2bf(v.z * r * gv.z);
  o.w = f2bf(v.w * r * gv.w);
  *(ushort4*)(out + (size_t)row * DIM + t * 4) = o;
}

// ---------------- addnorm: x += P0+P1+bias; h = rmsnorm(x,g) ----------------
__global__ __launch_bounds__(256) void addnorm_kernel(
    float* __restrict__ x, const float* __restrict__ P0,
    const float* __restrict__ P1, const float* __restrict__ bias,
    const float* __restrict__ g, u16* __restrict__ h) {
  int row = blockIdx.x;
  int t = threadIdx.x;
  float4 v = ((const float4*)(x + (size_t)row * DIM))[t];
  float4 a = ((const float4*)(P0 + (size_t)row * DIM))[t];
  float4 b = ((const float4*)(P1 + (size_t)row * DIM))[t];
  float4 c = ((const float4*)bias)[t];
  v.x += a.x + b.x + c.x;
  v.y += a.y + b.y + c.y;
  v.z += a.z + b.z + c.z;
  v.w += a.w + b.w + c.w;
  ((float4*)(x + (size_t)row * DIM))[t] = v;
  float ss = v.x * v.x + v.y * v.y + v.z * v.z + v.w * v.w;
  for (int off = 32; off > 0; off >>= 1) ss += __shfl_down(ss, off);
  __shared__ float part[4];
  if ((t & 63) == 0) part[t >> 6] = ss;
  __syncthreads();
  float tot = part[0] + part[1] + part[2] + part[3];
  float r = rsqrtf(tot / (float)DIM + 1e-6f);
  float4 gv = ((const float4*)g)[t];
  ushort4 o;
  o.x = f2bf(v.x * r * gv.x);
  o.y = f2bf(v.y * r * gv.y);
  o.z = f2bf(v.z * r * gv.z);
  o.w = f2bf(v.w * r * gv.w);
  *(ushort4*)(h + (size_t)row * DIM + t * 4) = o;
}

// ---------------- GEMM 128x128, double-buffered 2-phase ----------------
// SPLITK: grid=2*nm*nn, each slice does K/2, writes f32 partial (no bias).
template <int OUTBF, int SILU, int SPLITK, int MFAST>
__global__ __launch_bounds__(256, 2) void gemm128_kernel(
    const u16* __restrict__ A, const u16* __restrict__ Wt,
    const float* __restrict__ bias, void* __restrict__ outv,
    float* __restrict__ pout1, int M, int N, int K) {
  __shared__ u16 As[2][128 * 64];
  __shared__ u16 Bs[2][128 * 64];
  int nm = M >> 7, nn = N >> 7, nwg = nm * nn;
  int wg = xcd_swizzle(blockIdx.x, SPLITK ? nwg * 2 : nwg);
  int ks = 0;
  if (SPLITK) { ks = wg >= nwg; wg -= ks * nwg; }
  int mi, ni;
  if (MFAST) { mi = wg % nm; ni = wg / nm; }
  else       { ni = wg % nn; mi = wg / nn; }
  int m0 = mi << 7, n0 = ni << 7;
  int kb = SPLITK ? ks * (K >> 1) : 0;
  int NTt = (SPLITK ? (K >> 1) : K) >> 6;
  int tid = threadIdx.x, wave = tid >> 6, lane = tid & 63;
  int wr = wave >> 1, wc = wave & 1;
  int r16 = lane & 15, g4 = lane >> 4;
  int lrow = lane >> 3, lslot = lane & 7;

  f32x4 acc[4][4] = {};

  auto stage = [&](int buf, int kt) {
#pragma unroll
    for (int i = 0; i < 4; i++) {
      int s = wave * 4 + i;
      int row = s * 8 + lrow;
      int slot = lslot ^ (row & 7);
      gll16(A + (size_t)(m0 + row) * K + kb + kt * 64 + slot * 8,
            &As[buf][s * 512 + lane * 8]);
    }
#pragma unroll
    for (int i = 0; i < 4; i++) {
      int s = wave * 4 + i;
      int row = s * 8 + lrow;
      int slot = lslot ^ (row & 7);
      gll16(Wt + (size_t)(n0 + row) * K + kb + kt * 64 + slot * 8,
            &Bs[buf][s * 512 + lane * 8]);
    }
  };

  stage(0, 0);
  VMCNT(0);
  __builtin_amdgcn_s_barrier();

  for (int t = 0; t < NTt; t++) {
    int cur = t & 1;
    if (t + 1 < NTt) stage(cur ^ 1, t + 1);
#pragma unroll
    for (int kk = 0; kk < 2; kk++) {
      vshort8 af[4], bf[4];
#pragma unroll
      for (int m = 0; m < 4; m++) {
        int r = wr * 64 + m * 16 + r16;
        int slot = (kk * 4 + g4) ^ (r & 7);
        af[m] = *(const vshort8*)&As[cur][r * 64 + slot * 8];
      }
#pragma unroll
      for (int n = 0; n < 4; n++) {
        int c = wc * 64 + n * 16 + r16;
        int slot = (kk * 4 + g4) ^ (c & 7);
        bf[n] = *(const vshort8*)&Bs[cur][c * 64 + slot * 8];
      }
#pragma unroll
      for (int m = 0; m < 4; m++)
#pragma unroll
        for (int n = 0; n < 4; n++)
          acc[m][n] = __builtin_amdgcn_mfma_f32_16x16x32_bf16(af[m], bf[n],
                                                              acc[m][n], 0, 0, 0);
    }
    VMCNT(0);
    __builtin_amdgcn_s_barrier();
  }

  if (SPLITK) {
    float* P = ks ? pout1 : (float*)outv;
#pragma unroll
    for (int m = 0; m < 4; m++) {
      int rowb = m0 + wr * 64 + m * 16 + g4 * 4;
#pragma unroll
      for (int n = 0; n < 4; n++) {
        int col = n0 + wc * 64 + n * 16 + r16;
#pragma unroll
        for (int j = 0; j < 4; j++)
          P[(size_t)(rowb + j) * N + col] = acc[m][n][j];
      }
    }
  } else {
#pragma unroll
    for (int m = 0; m < 4; m++) {
      int rowb = m0 + wr * 64 + m * 16 + g4 * 4;
#pragma unroll
      for (int n = 0; n < 4; n++) {
        int col = n0 + wc * 64 + n * 16 + r16;
        float b = bias[col];
#pragma unroll
        for (int j = 0; j < 4; j++) {
          float v = acc[m][n][j] + b;
          if (SILU) v = v / (1.f + __expf(-v));
          if (OUTBF)
            ((u16*)outv)[(size_t)(rowb + j) * N + col] = f2bf(v);
          else
            ((float*)outv)[(size_t)(rowb + j) * N + col] = v;
        }
      }
    }
  }
}

// ---------------- GEMM 256x256, 8-phase, even per-phase staging ----------------
__global__ __launch_bounds__(512, 2) void gemm256_kernel(
    const u16* __restrict__ A, const u16* __restrict__ Wt,
    const float* __restrict__ bias, float* __restrict__ out,
    int M, int N, int K) {
  __shared__ u16 As[2][256 * 64];
  __shared__ u16 Bs[2][256 * 64];
  int nm = M >> 8, nn = N >> 8;
  int wg = xcd_swizzle(blockIdx.x, nm * nn);
  int mi = wg % nm, ni = wg / nm;
  int m0 = mi << 8, n0 = ni << 8;
  int tid = threadIdx.x, w = tid >> 6, lane = tid & 63;
  int wr = w >> 2, wc = w & 3;
  int r16 = lane & 15, g4 = lane >> 4;
  int srow8 = lane >> 3, sslot = lane & 7;
  int NT = K >> 6;

  f32x4 acc[8][4] = {};

  auto stageA = [&](int buf, int t, int hb, int j) {
    int chunk = j * 8 + w;
    int row = hb * 128 + chunk * 8 + srow8;
    int slot = sslot ^ (row & 7);
    gll16(A + (size_t)(m0 + row) * K + t * 64 + slot * 8,
          &As[buf][hb * 8192 + chunk * 512 + lane * 8]);
  };
  auto stageB = [&](int buf, int t, int hb, int j) {
    int chunk = j * 8 + w;
    int row = hb * 128 + chunk * 8 + srow8;
    int slot = sslot ^ (row & 7);
    gll16(Wt + (size_t)(n0 + row) * K + t * 64 + slot * 8,
          &Bs[buf][hb * 8192 + chunk * 512 + lane * 8]);
  };
  auto readA = [&](int buf, int mf, int kk) -> vshort8 {
    int row = mf * 32 + wr * 16 + r16;
    int slot = (kk * 4 + g4) ^ (row & 7);
    return *(const vshort8*)&As[buf][row * 64 + slot * 8];
  };
  auto readB = [&](int buf, int nf, int kk) -> vshort8 {
    int row = nf * 64 + wc * 16 + r16;
    int slot = (kk * 4 + g4) ^ (row & 7);
    return *(const vshort8*)&Bs[buf][row * 64 + slot * 8];
  };

  // prologue: stage tile 0 in order [A0, B0, B1, A1]
  stageA(0, 0, 0, 0); stageA(0, 0, 0, 1);
  stageB(0, 0, 0, 0); stageB(0, 0, 0, 1);
  stageB(0, 0, 1, 0); stageB(0, 0, 1, 1);
  stageA(0, 0, 1, 0); stageA(0, 0, 1, 1);
  VMCNT(0);
  __builtin_amdgcn_s_barrier();

  vshort8 af[4][2], bf0[2][2], bf1[2][2];

  for (int t = 0; t < NT; t++) {
    int cur = t & 1, nxt = cur ^ 1;
    bool hn = (t + 1 < NT);
    // ---- p0: (A0,B0). stage A0(t+1) ----
#pragma unroll
    for (int m = 0; m < 4; m++)
#pragma unroll
      for (int kk = 0; kk < 2; kk++) af[m][kk] = readA(cur, m, kk);
#pragma unroll
    for (int n = 0; n < 2; n++)
#pragma unroll
      for (int kk = 0; kk < 2; kk++) bf0[n][kk] = readB(cur, n, kk);
    if (hn) { stageA(nxt, t + 1, 0, 0); stageA(nxt, t + 1, 0, 1); }
    __builtin_amdgcn_s_barrier();
    __builtin_amdgcn_s_setprio(1);
#pragma unroll
    for (int m = 0; m < 4; m++)
#pragma unroll
      for (int n = 0; n < 2; n++)
#pragma unroll
        for (int kk = 0; kk < 2; kk++)
          acc[m][n] = __builtin_amdgcn_mfma_f32_16x16x32_bf16(
              af[m][kk], bf0[n][kk], acc[m][n], 0, 0, 0);
    __builtin_amdgcn_s_setprio(0);
    VMCNT(4);
    __builtin_amdgcn_s_barrier();
    // ---- p1: (A0,B1). stage B0(t+1) ----
#pragma unroll
    for (int n = 0; n < 2; n++)
#pragma unroll
      for (int kk = 0; kk < 2; kk++) bf1[n][kk] = readB(cur, 2 + n, kk);
    if (hn) { stageB(nxt, t + 1, 0, 0); stageB(nxt, t + 1, 0, 1); }
    __builtin_amdgcn_s_barrier();
    __builtin_amdgcn_s_setprio(1);
#pragma unroll
    for (int m = 0; m < 4; m++)
#pragma unroll
      for (int n = 0; n < 2; n++)
#pragma unroll
        for (int kk = 0; kk < 2; kk++)
          acc[m][n + 2] = __builtin_amdgcn_mfma_f32_16x16x32_bf16(
              af[m][kk], bf1[n][kk], acc[m][n + 2], 0, 0, 0);
    __builtin_amdgcn_s_setprio(0);
    VMCNT(4);
    __builtin_amdgcn_s_barrier();
    // ---- p2: (A1,B1). stage B1(t+1) ----
#pragma unroll
    for (int m = 0; m < 4; m++)
#pragma unroll
      for (int kk = 0; kk < 2; kk++) af[m][kk] = readA(cur, 4 + m, kk);
    if (hn) { stageB(nxt, t + 1, 1, 0); stageB(nxt, t + 1, 1, 1); }
    __builtin_amdgcn_s_barrier();
    __builtin_amdgcn_s_setprio(1);
#pragma unroll
    for (int m = 0; m < 4; m++)
#pragma unroll
      for (int n = 0; n < 2; n++)
#pragma unroll
        for (int kk = 0; kk < 2; kk++)
          acc[m + 4][n + 2] = __builtin_amdgcn_mfma_f32_16x16x32_bf16(
              af[m][kk], bf1[n][kk], acc[m + 4][n + 2], 0, 0, 0);
    __builtin_amdgcn_s_setprio(0);
    VMCNT(4);
    __builtin_amdgcn_s_barrier();
    // ---- p3: (A1,B0). stage A1(t+1) ----
#pragma unroll
    for (int n = 0; n < 2; n++)
#pragma unroll
      for (int kk = 0; kk < 2; kk++) bf0[n][kk] = readB(cur, n, kk);
    if (hn) { stageA(nxt, t + 1, 1, 0); stageA(nxt, t + 1, 1, 1); }
    __builtin_amdgcn_s_barrier();
    __builtin_amdgcn_s_setprio(1);
#pragma unroll
    for (int m = 0; m < 4; m++)
#pragma unroll
      for (int n = 0; n < 2; n++)
#pragma unroll
        for (int kk = 0; kk < 2; kk++)
          acc[m + 4][n] = __builtin_amdgcn_mfma_f32_16x16x32_bf16(
              af[m][kk], bf0[n][kk], acc[m + 4][n], 0, 0, 0);
    __builtin_amdgcn_s_setprio(0);
    VMCNT(4);
    __builtin_amdgcn_s_barrier();
  }

#pragma unroll
  for (int mf = 0; mf < 8; mf++) {
    int rowb = m0 + mf * 32 + wr * 16 + g4 * 4;
#pragma unroll
    for (int nf = 0; nf < 4; nf++) {
      int col = n0 + nf * 64 + wc * 16 + r16;
      float b = bias[col];
#pragma unroll
      for (int j = 0; j < 4; j++)
        out[(size_t)(rowb + j) * N + col] = acc[mf][nf][j] + b;
    }
  }
}

// ---------------- V slice of qkv -> vt2 [bh][S/8][64][8] ----------------
__global__ __launch_bounds__(256) void vtrans_kernel(const u16* __restrict__ qkv,
                                                     u16* __restrict__ vt2) {
  __shared__ u16 tl[64][80];
  int s0 = blockIdx.x * 64;
  int bh = blockIdx.y;
  int b = bh >> 4, h = bh & 15;
  int tid = threadIdx.x;
#pragma unroll
  for (int c = 0; c < 2; c++) {
    int idx = tid + c * 256;
    int row = idx >> 3;
    int col8 = (idx & 7) * 8;
    *(vshort8*)&tl[row][col8] = *(const vshort8*)
        &qkv[(size_t)(b * SEQ + s0 + row) * QKVN + 2 * DIM + h * HD + col8];
  }
  __syncthreads();
#pragma unroll
  for (int c = 0; c < 2; c++) {
    int idx = tid + c * 256;
    int s8l = idx >> 6;
    int d = idx & 63;
    vshort8 v;
#pragma unroll
    for (int j = 0; j < 8; j++) v[j] = (short)tl[s8l * 8 + j][d];
    *(vshort8*)&vt2[(((size_t)bh * (SEQ / 8) + (s0 >> 3) + s8l) * 64 + d) * 8] = v;
  }
}

// ---------------- flash attention: 4-wave blocks, LDS-staged K ----------------
__global__ __launch_bounds__(256) void attn_kernel(const u16* __restrict__ qkv,
                                                   const u16* __restrict__ vt2,
                                                   u16* __restrict__ o) {
  __shared__ u16 Ks[2][32 * 64];
  __shared__ u16 pl[4][16 * 40];
  int qblk = blockIdx.x, bh = blockIdx.y;
  int b = bh >> 4, h = bh & 15;
  int tid = threadIdx.x, w = tid >> 6, lane = tid & 63;
  int r16 = lane & 15, g4 = lane >> 4;
  int q0 = qblk * 64 + w * 16;

  const u16* qrow = qkv + ((size_t)(b * SEQ) + q0 + r16) * QKVN + h * HD;
  vshort8 aq0 = *(const vshort8*)(qrow + g4 * 8);
  vshort8 aq1 = *(const vshort8*)(qrow + 32 + g4 * 8);

  float mrun[4], lrun[4];
  f32x4 accO[4];
#pragma unroll
  for (int j = 0; j < 4; j++) { mrun[j] = -1e30f; lrun[j] = 0.f; }
#pragma unroll
  for (int d = 0; d < 4; d++) accO[d] = f32x4{0.f, 0.f, 0.f, 0.f};

  int nkvT = qblk * 2 + 2;
  auto stageK = [&](int buf, int kt) {
    int row = tid >> 3;
    int slot = (tid & 7) ^ (row & 7);
    gll16(qkv + ((size_t)(b * SEQ) + kt * 32 + row) * QKVN + DIM + h * HD + slot * 8,
          &Ks[buf][w * 512 + lane * 8]);
  };
  stageK(0, 0);
  __syncthreads();
  int buf = 0;
  for (int kt = 0; kt < nkvT; kt++) {
    int kv0 = kt * 32;
    if (kt + 1 < nkvT) stageK(buf ^ 1, kt + 1);
    if (kv0 <= q0 + 15) {
      int row0 = r16, row1 = 16 + r16;
      vshort8 bk00 = *(const vshort8*)&Ks[buf][row0 * 64 + ((0 + g4) ^ (row0 & 7)) * 8];
      vshort8 bk01 = *(const vshort8*)&Ks[buf][row0 * 64 + ((4 + g4) ^ (row0 & 7)) * 8];
      vshort8 bk10 = *(const vshort8*)&Ks[buf][row1 * 64 + ((0 + g4) ^ (row1 & 7)) * 8];
      vshort8 bk11 = *(const vshort8*)&Ks[buf][row1 * 64 + ((4 + g4) ^ (row1 & 7)) * 8];
      f32x4 s0 = {}, s1 = {};
      s0 = __builtin_amdgcn_mfma_f32_16x16x32_bf16(aq0, bk00, s0, 0, 0, 0);
      s0 = __builtin_amdgcn_mfma_f32_16x16x32_bf16(aq1, bk01, s0, 0, 0, 0);
      s1 = __builtin_amdgcn_mfma_f32_16x16x32_bf16(aq0, bk10, s1, 0, 0, 0);
      s1 = __builtin_amdgcn_mfma_f32_16x16x32_bf16(aq1, bk11, s1, 0, 0, 0);

#pragma unroll
      for (int j = 0; j < 4; j++) {
        int qg = q0 + g4 * 4 + j;
        float x0 = s0[j] * 0.125f;
        float x1 = s1[j] * 0.125f;
        if (kv0 + r16 > qg) x0 = -1e30f;
        if (kv0 + 16 + r16 > qg) x1 = -1e30f;
        float mx = fmaxf(x0, x1);
#pragma unroll
        for (int mm = 1; mm < 16; mm <<= 1) mx = fmaxf(mx, __shfl_xor(mx, mm));
        float mnew = fmaxf(mrun[j], mx);
        float alpha = __expf(mrun[j] - mnew);
        float p0 = __expf(x0 - mnew);
        float p1 = __expf(x1 - mnew);
        float rs = p0 + p1;
#pragma unroll
        for (int mm = 1; mm < 16; mm <<= 1) rs += __shfl_xor(rs, mm);
        lrun[j] = lrun[j] * alpha + rs;
        mrun[j] = mnew;
#pragma unroll
        for (int d = 0; d < 4; d++) accO[d][j] *= alpha;
        pl[w][(g4 * 4 + j) * 40 + r16] = f2bf(p0);
        pl[w][(g4 * 4 + j) * 40 + 16 + r16] = f2bf(p1);
      }
      asm volatile("s_waitcnt lgkmcnt(0)" ::: "memory");
      vshort8 ap = *(const vshort8*)&pl[w][r16 * 40 + g4 * 8];
      const u16* vbase = vt2 + (((size_t)bh * (SEQ / 8) + (kv0 >> 3) + g4) * 64) * 8;
#pragma unroll
      for (int d = 0; d < 4; d++) {
        vshort8 bv = *(const vshort8*)(vbase + (size_t)(d * 16 + r16) * 8);
        accO[d] = __builtin_amdgcn_mfma_f32_16x16x32_bf16(ap, bv, accO[d], 0, 0, 0);
      }
    }
    __syncthreads();
    buf ^= 1;
  }

#pragma unroll
  for (int j = 0; j < 4; j++) {
    float inv = 1.f / lrun[j];
    int row = q0 + g4 * 4 + j;
#pragma unroll
    for (int d = 0; d < 4; d++)
      o[((size_t)(b * SEQ) + row) * DIM + h * HD + d * 16 + r16] =
          f2bf(accO[d][j] * inv);
  }
}

// ---------------- host ----------------
extern "C" void kernel_launch(void* const* d_in, const int* in_sizes, int n_in,
                              void* d_out, int out_size, void* d_ws,
                              size_t ws_size, hipStream_t stream) {
  const int* ids = (const int*)d_in[0];
  const float* emb = (const float*)d_in[1];
  const float* g1 = (const float*)d_in[2];
  const float* wq = (const float*)d_in[3];
  const float* bq = (const float*)d_in[4];
  const float* wk = (const float*)d_in[5];
  const float* bk = (const float*)d_in[6];
  const float* wv = (const float*)d_in[7];
  const float* bv = (const float*)d_in[8];
  const float* wo = (const float*)d_in[9];
  const float* bo = (const float*)d_in[10];
  const float* g2 = (const float*)d_in[11];
  const float* w1 = (const float*)d_in[12];
  const float* b1 = (const float*)d_in[13];
  const float* w2 = (const float*)d_in[14];
  const float* b2 = (const float*)d_in[15];
  const float* gf = (const float*)d_in[16];
  const float* head_w = (const float*)d_in[17];
  const float* head_b = (const float*)d_in[18];
  float* out = (float*)d_out;

  char* ws = (char*)d_ws;
  size_t off = 0;
  auto alloc = [&](size_t bytes) -> char* {
    char* p = ws + off;
    off += (bytes + 255) & ~(size_t)255;
    return p;
  };
  u16* wqkvT = (u16*)alloc((size_t)LAYERS * QKVN * DIM * 2);
  u16* woT = (u16*)alloc((size_t)LAYERS * DIM * DIM * 2);
  u16* w1T = (u16*)alloc((size_t)LAYERS * DIM * FFN * 2);
  u16* w2T = (u16*)alloc((size_t)LAYERS * DIM * FFN * 2);
  u16* headT = (u16*)alloc((size_t)VOCAB * DIM * 2);
  float* bqkv = (float*)alloc((size_t)LAYERS * QKVN * 4);
  float* x = (float*)alloc((size_t)ROWS * DIM * 4);
  u16* h = (u16*)alloc((size_t)ROWS * DIM * 2);
  u16* qkvb = (u16*)alloc((size_t)ROWS * QKVN * 2);
  u16* vtb = (u16*)alloc((size_t)ROWS * DIM * 2);
  u16* ob = (u16*)alloc((size_t)ROWS * DIM * 2);
  u16* tb = (u16*)alloc((size_t)ROWS * FFN * 2);
  float* P0 = (float*)alloc((size_t)ROWS * DIM * 4);
  float* P1 = (float*)alloc((size_t)ROWS * DIM * 4);
  if (off > ws_size) return;

  dim3 tb32(32, 8);
  for (int l = 0; l < LAYERS; l++) {
    u16* base = wqkvT + (size_t)l * QKVN * DIM;
    transpose_f32_bf16<<<dim3(DIM / 32, DIM / 32), tb32, 0, stream>>>(
        wq + (size_t)l * DIM * DIM, base, DIM, DIM);
    transpose_f32_bf16<<<dim3(DIM / 32, DIM / 32), tb32, 0, stream>>>(
        wk + (size_t)l * DIM * DIM, base + (size_t)DIM * DIM, DIM, DIM);
    transpose_f32_bf16<<<dim3(DIM / 32, DIM / 32), tb32, 0, stream>>>(
        wv + (size_t)l * DIM * DIM, base + (size_t)2 * DIM * DIM, DIM, DIM);
    transpose_f32_bf16<<<dim3(DIM / 32, DIM / 32), tb32, 0, stream>>>(
        wo + (size_t)l * DIM * DIM, woT + (size_t)l * DIM * DIM, DIM, DIM);
    transpose_f32_bf16<<<dim3(FFN / 32, DIM / 32), tb32, 0, stream>>>(
        w1 + (size_t)l * DIM * FFN, w1T + (size_t)l * DIM * FFN, DIM, FFN);
    transpose_f32_bf16<<<dim3(DIM / 32, FFN / 32), tb32, 0, stream>>>(
        w2 + (size_t)l * DIM * FFN, w2T + (size_t)l * DIM * FFN, FFN, DIM);
    pack_qkv_bias<<<QKVN / 256, 256, 0, stream>>>(
        bq + (size_t)l * DIM, bk + (size_t)l * DIM, bv + (size_t)l * DIM,
        bqkv + (size_t)l * QKVN);
  }
  transpose_f32_bf16<<<dim3(VOCAB / 32, DIM / 32), tb32, 0, stream>>>(
      head_w, headT, DIM, VOCAB);

  embed_gather<<<ROWS, 256, 0, stream>>>(ids, emb, x);
  rmsnorm_kernel<<<ROWS, 256, 0, stream>>>(x, g1, h);

  for (int l = 0; l < LAYERS; l++) {
    gemm128_kernel<1, 0, 0, 1>
        <<<(ROWS / 128) * (QKVN / 128), 256, 0, stream>>>(
            h, wqkvT + (size_t)l * QKVN * DIM, bqkv + (size_t)l * QKVN,
            qkvb, nullptr, ROWS, QKVN, DIM);
    vtrans_kernel<<<dim3(SEQ / 64, BATCH * HEADS), 256, 0, stream>>>(qkvb, vtb);
    attn_kernel<<<dim3(SEQ / 64, BATCH * HEADS), 256, 0, stream>>>(qkvb, vtb, ob);
    gemm128_kernel<0, 0, 1, 0>
        <<<2 * (ROWS / 128) * (DIM / 128), 256, 0, stream>>>(
            ob, woT + (size_t)l * DIM * DIM, nullptr, P0, P1, ROWS, DIM, DIM);
    addnorm_kernel<<<ROWS, 256, 0, stream>>>(
        x, P0, P1, bo + (size_t)l * DIM, g2 + (size_t)l * DIM, h);
    gemm128_kernel<1, 1, 0, 1>
        <<<(ROWS / 128) * (FFN / 128), 256, 0, stream>>>(
            h, w1T + (size_t)l * DIM * FFN, b1 + (size_t)l * FFN, tb, nullptr,
            ROWS, FFN, DIM);
    gemm128_kernel<0, 0, 1, 0>
        <<<2 * (ROWS / 128) * (DIM / 128), 256, 0, stream>>>(
            tb, w2T + (size_t)l * DIM * FFN, nullptr, P0, P1, ROWS, DIM, FFN);
    addnorm_kernel<<<ROWS, 256, 0, stream>>>(
        x, P0, P1, b2 + (size_t)l * DIM,
        (l == LAYERS - 1) ? gf : (g1 + (size_t)(l + 1) * DIM), h);
  }
  gemm256_kernel<<<(ROWS / 256) * (VOCAB / 256), 512, 0, stream>>>(
      h, headT, head_b, out, ROWS, VOCAB, DIM);
}

// Round 5
// 634.217 us; speedup vs baseline: 1.3227x; 1.0579x over previous
//
#include <hip/hip_runtime.h>

#define LAYERS 2
#define DIM 1024
#define HEADS 16
#define HD 64
#define BATCH 2
#define SEQ 1024
#define ROWS (BATCH * SEQ) /* 2048 */
#define FFN (4 * DIM)      /* 4096 */
#define VOCAB 32000
#define QKVN (3 * DIM) /* 3072 */

typedef unsigned short u16;
typedef short vshort8 __attribute__((ext_vector_type(8)));
typedef float f32x4 __attribute__((ext_vector_type(4)));

#define VMCNT(n) asm volatile("s_waitcnt vmcnt(" #n ")" ::: "memory")

__device__ __forceinline__ u16 f2bf(float f) {
  union { float f; unsigned u; } x{f};
  unsigned r = (x.u + 0x7fffu + ((x.u >> 16) & 1u)) >> 16;
  return (u16)r;
}

__device__ __forceinline__ void gll16(const void* g, u16* l) {
  __builtin_amdgcn_global_load_lds(
      (const __attribute__((address_space(1))) void*)g,
      (__attribute__((address_space(3))) void*)l, 16, 0, 0);
}

// bijective XCD swizzle (m204)
__device__ __forceinline__ int xcd_swizzle(int orig, int nwg) {
  int q = nwg >> 3, r = nwg & 7;
  int xcd = orig & 7;
  int base = (xcd < r) ? xcd * (q + 1) : r * (q + 1) + (xcd - r) * q;
  return base + (orig >> 3);
}

// ---------------- transpose f32 [R,C] -> bf16 [C,R] ----------------
__global__ __launch_bounds__(256) void transpose_f32_bf16(
    const float* __restrict__ src, u16* __restrict__ dst, int R, int C) {
  __shared__ float tile[32][33];
  int c0 = blockIdx.x * 32, r0 = blockIdx.y * 32;
  int tx = threadIdx.x, ty = threadIdx.y;  // (32,8)
#pragma unroll
  for (int i = 0; i < 4; i++)
    tile[ty + i * 8][tx] = src[(size_t)(r0 + ty + i * 8) * C + c0 + tx];
  __syncthreads();
#pragma unroll
  for (int i = 0; i < 4; i++)
    dst[(size_t)(c0 + ty + i * 8) * R + r0 + tx] = f2bf(tile[tx][ty + i * 8]);
}

// ---------------- pack q/k/v biases into one [3072] vector ----------------
__global__ __launch_bounds__(256) void pack_qkv_bias(
    const float* __restrict__ bq, const float* __restrict__ bk,
    const float* __restrict__ bv, float* __restrict__ o) {
  int t = blockIdx.x * 256 + threadIdx.x;
  if (t < DIM) o[t] = bq[t];
  else if (t < 2 * DIM) o[t] = bk[t - DIM];
  else if (t < 3 * DIM) o[t] = bv[t - 2 * DIM];
}

// ---------------- embedding gather ----------------
__global__ __launch_bounds__(256) void embed_gather(
    const int* __restrict__ ids, const float* __restrict__ emb,
    float* __restrict__ x) {
  int row = blockIdx.x;
  int id = ids[row];
  const float4* s = (const float4*)(emb + (size_t)id * DIM);
  float4* d = (float4*)(x + (size_t)row * DIM);
  d[threadIdx.x] = s[threadIdx.x];
}

// ---------------- rmsnorm: f32 in -> bf16 out ----------------
__global__ __launch_bounds__(256) void rmsnorm_kernel(
    const float* __restrict__ x, const float* __restrict__ g,
    u16* __restrict__ out) {
  int row = blockIdx.x;
  int t = threadIdx.x;
  const float4* xr = (const float4*)(x + (size_t)row * DIM);
  float4 v = xr[t];
  float ss = v.x * v.x + v.y * v.y + v.z * v.z + v.w * v.w;
  for (int off = 32; off > 0; off >>= 1) ss += __shfl_down(ss, off);
  __shared__ float part[4];
  if ((t & 63) == 0) part[t >> 6] = ss;
  __syncthreads();
  float tot = part[0] + part[1] + part[2] + part[3];
  float r = rsqrtf(tot / (float)DIM + 1e-6f);
  float4 gv = ((const float4*)g)[t];
  ushort4 o;
  o.x = f2bf(v.x * r * gv.x);
  o.y = f2bf(v.y * r * gv.y);
  o.z = f2bf(v.z * r * gv.z);
  o.w = f2bf(v.w * r * gv.w);
  *(ushort4*)(out + (size_t)row * DIM + t * 4) = o;
}

// ---------------- addnorm: x += P0+P1+bias; h = rmsnorm(x,g) ----------------
__global__ __launch_bounds__(256) void addnorm_kernel(
    float* __restrict__ x, const float* __restrict__ P0,
    const float* __restrict__ P1, const float* __restrict__ bias,
    const float* __restrict__ g, u16* __restrict__ h) {
  int row = blockIdx.x;
  int t = threadIdx.x;
  float4 v = ((const float4*)(x + (size_t)row * DIM))[t];
  float4 a = ((const float4*)(P0 + (size_t)row * DIM))[t];
  float4 b = ((const float4*)(P1 + (size_t)row * DIM))[t];
  float4 c = ((const float4*)bias)[t];
  v.x += a.x + b.x + c.x;
  v.y += a.y + b.y + c.y;
  v.z += a.z + b.z + c.z;
  v.w += a.w + b.w + c.w;
  ((float4*)(x + (size_t)row * DIM))[t] = v;
  float ss = v.x * v.x + v.y * v.y + v.z * v.z + v.w * v.w;
  for (int off = 32; off > 0; off >>= 1) ss += __shfl_down(ss, off);
  __shared__ float part[4];
  if ((t & 63) == 0) part[t >> 6] = ss;
  __syncthreads();
  float tot = part[0] + part[1] + part[2] + part[3];
  float r = rsqrtf(tot / (float)DIM + 1e-6f);
  float4 gv = ((const float4*)g)[t];
  ushort4 o;
  o.x = f2bf(v.x * r * gv.x);
  o.y = f2bf(v.y * r * gv.y);
  o.z = f2bf(v.z * r * gv.z);
  o.w = f2bf(v.w * r * gv.w);
  *(ushort4*)(h + (size_t)row * DIM + t * 4) = o;
}

// ---------------- GEMM 128x128, double-buffered 2-phase ----------------
template <int OUTBF, int SILU, int SPLITK, int MFAST>
__global__ __launch_bounds__(256, 2) void gemm128_kernel(
    const u16* __restrict__ A, const u16* __restrict__ Wt,
    const float* __restrict__ bias, void* __restrict__ outv,
    float* __restrict__ pout1, int M, int N, int K) {
  __shared__ u16 As[2][128 * 64];
  __shared__ u16 Bs[2][128 * 64];
  int nm = M >> 7, nn = N >> 7, nwg = nm * nn;
  int wg = xcd_swizzle(blockIdx.x, SPLITK ? nwg * 2 : nwg);
  int ks = 0;
  if (SPLITK) { ks = wg >= nwg; wg -= ks * nwg; }
  int mi, ni;
  if (MFAST) { mi = wg % nm; ni = wg / nm; }
  else       { ni = wg % nn; mi = wg / nn; }
  int m0 = mi << 7, n0 = ni << 7;
  int kb = SPLITK ? ks * (K >> 1) : 0;
  int NTt = (SPLITK ? (K >> 1) : K) >> 6;
  int tid = threadIdx.x, wave = tid >> 6, lane = tid & 63;
  int wr = wave >> 1, wc = wave & 1;
  int r16 = lane & 15, g4 = lane >> 4;
  int lrow = lane >> 3, lslot = lane & 7;

  f32x4 acc[4][4] = {};

  auto stage = [&](int buf, int kt) {
#pragma unroll
    for (int i = 0; i < 4; i++) {
      int s = wave * 4 + i;
      int row = s * 8 + lrow;
      int slot = lslot ^ (row & 7);
      gll16(A + (size_t)(m0 + row) * K + kb + kt * 64 + slot * 8,
            &As[buf][s * 512 + lane * 8]);
    }
#pragma unroll
    for (int i = 0; i < 4; i++) {
      int s = wave * 4 + i;
      int row = s * 8 + lrow;
      int slot = lslot ^ (row & 7);
      gll16(Wt + (size_t)(n0 + row) * K + kb + kt * 64 + slot * 8,
            &Bs[buf][s * 512 + lane * 8]);
    }
  };

  stage(0, 0);
  VMCNT(0);
  __builtin_amdgcn_s_barrier();

  for (int t = 0; t < NTt; t++) {
    int cur = t & 1;
    if (t + 1 < NTt) stage(cur ^ 1, t + 1);
#pragma unroll
    for (int kk = 0; kk < 2; kk++) {
      vshort8 af[4], bf[4];
#pragma unroll
      for (int m = 0; m < 4; m++) {
        int r = wr * 64 + m * 16 + r16;
        int slot = (kk * 4 + g4) ^ (r & 7);
        af[m] = *(const vshort8*)&As[cur][r * 64 + slot * 8];
      }
#pragma unroll
      for (int n = 0; n < 4; n++) {
        int c = wc * 64 + n * 16 + r16;
        int slot = (kk * 4 + g4) ^ (c & 7);
        bf[n] = *(const vshort8*)&Bs[cur][c * 64 + slot * 8];
      }
#pragma unroll
      for (int m = 0; m < 4; m++)
#pragma unroll
        for (int n = 0; n < 4; n++)
          acc[m][n] = __builtin_amdgcn_mfma_f32_16x16x32_bf16(af[m], bf[n],
                                                              acc[m][n], 0, 0, 0);
    }
    VMCNT(0);
    __builtin_amdgcn_s_barrier();
  }

  if (SPLITK) {
    float* P = ks ? pout1 : (float*)outv;
#pragma unroll
    for (int m = 0; m < 4; m++) {
      int rowb = m0 + wr * 64 + m * 16 + g4 * 4;
#pragma unroll
      for (int n = 0; n < 4; n++) {
        int col = n0 + wc * 64 + n * 16 + r16;
#pragma unroll
        for (int j = 0; j < 4; j++)
          P[(size_t)(rowb + j) * N + col] = acc[m][n][j];
      }
    }
  } else {
#pragma unroll
    for (int m = 0; m < 4; m++) {
      int rowb = m0 + wr * 64 + m * 16 + g4 * 4;
#pragma unroll
      for (int n = 0; n < 4; n++) {
        int col = n0 + wc * 64 + n * 16 + r16;
        float b = bias[col];
#pragma unroll
        for (int j = 0; j < 4; j++) {
          float v = acc[m][n][j] + b;
          if (SILU) v = v / (1.f + __expf(-v));
          if (OUTBF)
            ((u16*)outv)[(size_t)(rowb + j) * N + col] = f2bf(v);
          else
            ((float*)outv)[(size_t)(rowb + j) * N + col] = v;
        }
      }
    }
  }
}

// ---------------- persistent 256x256 8-phase head GEMM ----------------
// 250 blocks; block = (n-tile, m-half); 4 m-tiles per block = 64 K-tile
// continuous pipeline; staging runs across tile boundaries; epilogue
// (async stores) inserted at boundaries only. Requires M=2048, K=1024.
__global__ __launch_bounds__(512, 2) void gemm256p_kernel(
    const u16* __restrict__ A, const u16* __restrict__ Wt,
    const float* __restrict__ bias, float* __restrict__ out,
    int M, int N, int K) {
  __shared__ u16 As[2][256 * 64];
  __shared__ u16 Bs[2][256 * 64];
  int nn = N >> 8;
  int wg = xcd_swizzle(blockIdx.x, nn * 2);
  int ni = wg >> 1, mhalf = wg & 1;
  int n0 = ni << 8;
  int tid = threadIdx.x, w = tid >> 6, lane = tid & 63;
  int wr = w >> 2, wc = w & 3;
  int r16 = lane & 15, g4 = lane >> 4;
  int srow8 = lane >> 3, sslot = lane & 7;
  const int NTK = 16;  // K/64 == 16 (K=1024)
  const int NGT = 64;  // 4 tiles x 16

  f32x4 acc[8][4] = {};

  auto stageA = [&](int buf, int mb, int kt, int hb, int j) {
    int chunk = j * 8 + w;
    int row = hb * 128 + chunk * 8 + srow8;
    int slot = sslot ^ (row & 7);
    gll16(A + (size_t)(mb + row) * K + kt * 64 + slot * 8,
          &As[buf][hb * 8192 + chunk * 512 + lane * 8]);
  };
  auto stageB = [&](int buf, int kt, int hb, int j) {
    int chunk = j * 8 + w;
    int row = hb * 128 + chunk * 8 + srow8;
    int slot = sslot ^ (row & 7);
    gll16(Wt + (size_t)(n0 + row) * K + kt * 64 + slot * 8,
          &Bs[buf][hb * 8192 + chunk * 512 + lane * 8]);
  };
  auto readA = [&](int buf, int mf, int kk) -> vshort8 {
    int row = mf * 32 + wr * 16 + r16;
    int slot = (kk * 4 + g4) ^ (row & 7);
    return *(const vshort8*)&As[buf][row * 64 + slot * 8];
  };
  auto readB = [&](int buf, int nf, int kk) -> vshort8 {
    int row = nf * 64 + wc * 16 + r16;
    int slot = (kk * 4 + g4) ^ (row & 7);
    return *(const vshort8*)&Bs[buf][row * 64 + slot * 8];
  };

  // prologue: stage K-tile 0 of m-tile 0: [A0, B0, B1, A1]
  int mb0 = (mhalf * 4) << 8;
  stageA(0, mb0, 0, 0, 0); stageA(0, mb0, 0, 0, 1);
  stageB(0, 0, 0, 0);      stageB(0, 0, 0, 1);
  stageB(0, 0, 1, 0);      stageB(0, 0, 1, 1);
  stageA(0, mb0, 0, 1, 0); stageA(0, mb0, 0, 1, 1);
  VMCNT(0);
  __builtin_amdgcn_s_barrier();

  vshort8 af[4][2], bf0[2][2], bf1[2][2];

  for (int ti = 0; ti < 4; ti++) {
    int m0 = (mhalf * 4 + ti) << 8;
    for (int tt = 0; tt < NTK; tt++) {
      int gt = ti * NTK + tt;
      int cur = gt & 1, nxt = cur ^ 1;
      int gt1 = gt + 1;
      bool hn = gt1 < NGT;
      int kt1 = gt1 & (NTK - 1);
      int mb1 = (mhalf * 4 + (gt1 >> 4)) << 8;
      // ---- p0: (A0,B0). stage A0(next) ----
#pragma unroll
      for (int m = 0; m < 4; m++)
#pragma unroll
        for (int kk = 0; kk < 2; kk++) af[m][kk] = readA(cur, m, kk);
#pragma unroll
      for (int n = 0; n < 2; n++)
#pragma unroll
        for (int kk = 0; kk < 2; kk++) bf0[n][kk] = readB(cur, n, kk);
      if (hn) { stageA(nxt, mb1, kt1, 0, 0); stageA(nxt, mb1, kt1, 0, 1); }
      __builtin_amdgcn_s_barrier();
      __builtin_amdgcn_s_setprio(1);
#pragma unroll
      for (int m = 0; m < 4; m++)
#pragma unroll
        for (int n = 0; n < 2; n++)
#pragma unroll
          for (int kk = 0; kk < 2; kk++)
            acc[m][n] = __builtin_amdgcn_mfma_f32_16x16x32_bf16(
                af[m][kk], bf0[n][kk], acc[m][n], 0, 0, 0);
      __builtin_amdgcn_s_setprio(0);
      VMCNT(4);
      __builtin_amdgcn_s_barrier();
      // ---- p1: (A0,B1). stage B0(next) ----
#pragma unroll
      for (int n = 0; n < 2; n++)
#pragma unroll
        for (int kk = 0; kk < 2; kk++) bf1[n][kk] = readB(cur, 2 + n, kk);
      if (hn) { stageB(nxt, kt1, 0, 0); stageB(nxt, kt1, 0, 1); }
      __builtin_amdgcn_s_barrier();
      __builtin_amdgcn_s_setprio(1);
#pragma unroll
      for (int m = 0; m < 4; m++)
#pragma unroll
        for (int n = 0; n < 2; n++)
#pragma unroll
          for (int kk = 0; kk < 2; kk++)
            acc[m][n + 2] = __builtin_amdgcn_mfma_f32_16x16x32_bf16(
                af[m][kk], bf1[n][kk], acc[m][n + 2], 0, 0, 0);
      __builtin_amdgcn_s_setprio(0);
      VMCNT(4);
      __builtin_amdgcn_s_barrier();
      // ---- p2: (A1,B1). stage B1(next) ----
#pragma unroll
      for (int m = 0; m < 4; m++)
#pragma unroll
        for (int kk = 0; kk < 2; kk++) af[m][kk] = readA(cur, 4 + m, kk);
      if (hn) { stageB(nxt, kt1, 1, 0); stageB(nxt, kt1, 1, 1); }
      __builtin_amdgcn_s_barrier();
      __builtin_amdgcn_s_setprio(1);
#pragma unroll
      for (int m = 0; m < 4; m++)
#pragma unroll
        for (int n = 0; n < 2; n++)
#pragma unroll
          for (int kk = 0; kk < 2; kk++)
            acc[m + 4][n + 2] = __builtin_amdgcn_mfma_f32_16x16x32_bf16(
                af[m][kk], bf1[n][kk], acc[m + 4][n + 2], 0, 0, 0);
      __builtin_amdgcn_s_setprio(0);
      VMCNT(4);
      __builtin_amdgcn_s_barrier();
      // ---- p3: (A1,B0 from regs — no LDS reads). stage A1(next) ----
      if (hn) { stageA(nxt, mb1, kt1, 1, 0); stageA(nxt, mb1, kt1, 1, 1); }
      __builtin_amdgcn_s_barrier();
      __builtin_amdgcn_s_setprio(1);
#pragma unroll
      for (int m = 0; m < 4; m++)
#pragma unroll
        for (int n = 0; n < 2; n++)
#pragma unroll
          for (int kk = 0; kk < 2; kk++)
            acc[m + 4][n] = __builtin_amdgcn_mfma_f32_16x16x32_bf16(
                af[m][kk], bf0[n][kk], acc[m + 4][n], 0, 0, 0);
      __builtin_amdgcn_s_setprio(0);
      VMCNT(4);
      __builtin_amdgcn_s_barrier();
    }
    // ---- tile epilogue: async stores, re-zero acc, keep pipeline going ----
#pragma unroll
    for (int mf = 0; mf < 8; mf++) {
      int rowb = m0 + mf * 32 + wr * 16 + g4 * 4;
#pragma unroll
      for (int nf = 0; nf < 4; nf++) {
        int col = n0 + nf * 64 + wc * 16 + r16;
        float b = bias[col];
#pragma unroll
        for (int j = 0; j < 4; j++)
          out[(size_t)(rowb + j) * N + col] = acc[mf][nf][j] + b;
      }
    }
#pragma unroll
    for (int mf = 0; mf < 8; mf++)
#pragma unroll
      for (int nf = 0; nf < 4; nf++) acc[mf][nf] = f32x4{0.f, 0.f, 0.f, 0.f};
  }
}

// ---------------- V slice of qkv -> vt2 [bh][S/8][64][8] ----------------
__global__ __launch_bounds__(256) void vtrans_kernel(const u16* __restrict__ qkv,
                                                     u16* __restrict__ vt2) {
  __shared__ u16 tl[64][80];
  int s0 = blockIdx.x * 64;
  int bh = blockIdx.y;
  int b = bh >> 4, h = bh & 15;
  int tid = threadIdx.x;
#pragma unroll
  for (int c = 0; c < 2; c++) {
    int idx = tid + c * 256;
    int row = idx >> 3;
    int col8 = (idx & 7) * 8;
    *(vshort8*)&tl[row][col8] = *(const vshort8*)
        &qkv[(size_t)(b * SEQ + s0 + row) * QKVN + 2 * DIM + h * HD + col8];
  }
  __syncthreads();
#pragma unroll
  for (int c = 0; c < 2; c++) {
    int idx = tid + c * 256;
    int s8l = idx >> 6;
    int d = idx & 63;
    vshort8 v;
#pragma unroll
    for (int j = 0; j < 8; j++) v[j] = (short)tl[s8l * 8 + j][d];
    *(vshort8*)&vt2[(((size_t)bh * (SEQ / 8) + (s0 >> 3) + s8l) * 64 + d) * 8] = v;
  }
}

// ---------------- flash attention: 4-wave blocks, LDS-staged K ----------------
__global__ __launch_bounds__(256) void attn_kernel(const u16* __restrict__ qkv,
                                                   const u16* __restrict__ vt2,
                                                   u16* __restrict__ o) {
  __shared__ u16 Ks[2][32 * 64];
  __shared__ u16 pl[4][16 * 40];
  int qblk = blockIdx.x, bh = blockIdx.y;
  int b = bh >> 4, h = bh & 15;
  int tid = threadIdx.x, w = tid >> 6, lane = tid & 63;
  int r16 = lane & 15, g4 = lane >> 4;
  int q0 = qblk * 64 + w * 16;

  const u16* qrow = qkv + ((size_t)(b * SEQ) + q0 + r16) * QKVN + h * HD;
  vshort8 aq0 = *(const vshort8*)(qrow + g4 * 8);
  vshort8 aq1 = *(const vshort8*)(qrow + 32 + g4 * 8);

  float mrun[4], lrun[4];
  f32x4 accO[4];
#pragma unroll
  for (int j = 0; j < 4; j++) { mrun[j] = -1e30f; lrun[j] = 0.f; }
#pragma unroll
  for (int d = 0; d < 4; d++) accO[d] = f32x4{0.f, 0.f, 0.f, 0.f};

  int nkvT = qblk * 2 + 2;
  auto stageK = [&](int buf, int kt) {
    int row = tid >> 3;
    int slot = (tid & 7) ^ (row & 7);
    gll16(qkv + ((size_t)(b * SEQ) + kt * 32 + row) * QKVN + DIM + h * HD + slot * 8,
          &Ks[buf][w * 512 + lane * 8]);
  };
  stageK(0, 0);
  __syncthreads();
  int buf = 0;
  for (int kt = 0; kt < nkvT; kt++) {
    int kv0 = kt * 32;
    if (kt + 1 < nkvT) stageK(buf ^ 1, kt + 1);
    if (kv0 <= q0 + 15) {
      int row0 = r16, row1 = 16 + r16;
      vshort8 bk00 = *(const vshort8*)&Ks[buf][row0 * 64 + ((0 + g4) ^ (row0 & 7)) * 8];
      vshort8 bk01 = *(const vshort8*)&Ks[buf][row0 * 64 + ((4 + g4) ^ (row0 & 7)) * 8];
      vshort8 bk10 = *(const vshort8*)&Ks[buf][row1 * 64 + ((0 + g4) ^ (row1 & 7)) * 8];
      vshort8 bk11 = *(const vshort8*)&Ks[buf][row1 * 64 + ((4 + g4) ^ (row1 & 7)) * 8];
      f32x4 s0 = {}, s1 = {};
      s0 = __builtin_amdgcn_mfma_f32_16x16x32_bf16(aq0, bk00, s0, 0, 0, 0);
      s0 = __builtin_amdgcn_mfma_f32_16x16x32_bf16(aq1, bk01, s0, 0, 0, 0);
      s1 = __builtin_amdgcn_mfma_f32_16x16x32_bf16(aq0, bk10, s1, 0, 0, 0);
      s1 = __builtin_amdgcn_mfma_f32_16x16x32_bf16(aq1, bk11, s1, 0, 0, 0);

#pragma unroll
      for (int j = 0; j < 4; j++) {
        int qg = q0 + g4 * 4 + j;
        float x0 = s0[j] * 0.125f;
        float x1 = s1[j] * 0.125f;
        if (kv0 + r16 > qg) x0 = -1e30f;
        if (kv0 + 16 + r16 > qg) x1 = -1e30f;
        float mx = fmaxf(x0, x1);
#pragma unroll
        for (int mm = 1; mm < 16; mm <<= 1) mx = fmaxf(mx, __shfl_xor(mx, mm));
        float mnew = fmaxf(mrun[j], mx);
        float alpha = __expf(mrun[j] - mnew);
        float p0 = __expf(x0 - mnew);
        float p1 = __expf(x1 - mnew);
        float rs = p0 + p1;
#pragma unroll
        for (int mm = 1; mm < 16; mm <<= 1) rs += __shfl_xor(rs, mm);
        lrun[j] = lrun[j] * alpha + rs;
        mrun[j] = mnew;
#pragma unroll
        for (int d = 0; d < 4; d++) accO[d][j] *= alpha;
        pl[w][(g4 * 4 + j) * 40 + r16] = f2bf(p0);
        pl[w][(g4 * 4 + j) * 40 + 16 + r16] = f2bf(p1);
      }
      asm volatile("s_waitcnt lgkmcnt(0)" ::: "memory");
      vshort8 ap = *(const vshort8*)&pl[w][r16 * 40 + g4 * 8];
      const u16* vbase = vt2 + (((size_t)bh * (SEQ / 8) + (kv0 >> 3) + g4) * 64) * 8;
#pragma unroll
      for (int d = 0; d < 4; d++) {
        vshort8 bv = *(const vshort8*)(vbase + (size_t)(d * 16 + r16) * 8);
        accO[d] = __builtin_amdgcn_mfma_f32_16x16x32_bf16(ap, bv, accO[d], 0, 0, 0);
      }
    }
    __syncthreads();
    buf ^= 1;
  }

#pragma unroll
  for (int j = 0; j < 4; j++) {
    float inv = 1.f / lrun[j];
    int row = q0 + g4 * 4 + j;
#pragma unroll
    for (int d = 0; d < 4; d++)
      o[((size_t)(b * SEQ) + row) * DIM + h * HD + d * 16 + r16] =
          f2bf(accO[d][j] * inv);
  }
}

// ---------------- host ----------------
extern "C" void kernel_launch(void* const* d_in, const int* in_sizes, int n_in,
                              void* d_out, int out_size, void* d_ws,
                              size_t ws_size, hipStream_t stream) {
  const int* ids = (const int*)d_in[0];
  const float* emb = (const float*)d_in[1];
  const float* g1 = (const float*)d_in[2];
  const float* wq = (const float*)d_in[3];
  const float* bq = (const float*)d_in[4];
  const float* wk = (const float*)d_in[5];
  const float* bk = (const float*)d_in[6];
  const float* wv = (const float*)d_in[7];
  const float* bv = (const float*)d_in[8];
  const float* wo = (const float*)d_in[9];
  const float* bo = (const float*)d_in[10];
  const float* g2 = (const float*)d_in[11];
  const float* w1 = (const float*)d_in[12];
  const float* b1 = (const float*)d_in[13];
  const float* w2 = (const float*)d_in[14];
  const float* b2 = (const float*)d_in[15];
  const float* gf = (const float*)d_in[16];
  const float* head_w = (const float*)d_in[17];
  const float* head_b = (const float*)d_in[18];
  float* out = (float*)d_out;

  char* ws = (char*)d_ws;
  size_t off = 0;
  auto alloc = [&](size_t bytes) -> char* {
    char* p = ws + off;
    off += (bytes + 255) & ~(size_t)255;
    return p;
  };
  u16* wqkvT = (u16*)alloc((size_t)LAYERS * QKVN * DIM * 2);
  u16* woT = (u16*)alloc((size_t)LAYERS * DIM * DIM * 2);
  u16* w1T = (u16*)alloc((size_t)LAYERS * DIM * FFN * 2);
  u16* w2T = (u16*)alloc((size_t)LAYERS * DIM * FFN * 2);
  u16* headT = (u16*)alloc((size_t)VOCAB * DIM * 2);
  float* bqkv = (float*)alloc((size_t)LAYERS * QKVN * 4);
  float* x = (float*)alloc((size_t)ROWS * DIM * 4);
  u16* h = (u16*)alloc((size_t)ROWS * DIM * 2);
  u16* qkvb = (u16*)alloc((size_t)ROWS * QKVN * 2);
  u16* vtb = (u16*)alloc((size_t)ROWS * DIM * 2);
  u16* ob = (u16*)alloc((size_t)ROWS * DIM * 2);
  u16* tb = (u16*)alloc((size_t)ROWS * FFN * 2);
  float* P0 = (float*)alloc((size_t)ROWS * DIM * 4);
  float* P1 = (float*)alloc((size_t)ROWS * DIM * 4);
  if (off > ws_size) return;

  dim3 tb32(32, 8);
  for (int l = 0; l < LAYERS; l++) {
    u16* base = wqkvT + (size_t)l * QKVN * DIM;
    transpose_f32_bf16<<<dim3(DIM / 32, DIM / 32), tb32, 0, stream>>>(
        wq + (size_t)l * DIM * DIM, base, DIM, DIM);
    transpose_f32_bf16<<<dim3(DIM / 32, DIM / 32), tb32, 0, stream>>>(
        wk + (size_t)l * DIM * DIM, base + (size_t)DIM * DIM, DIM, DIM);
    transpose_f32_bf16<<<dim3(DIM / 32, DIM / 32), tb32, 0, stream>>>(
        wv + (size_t)l * DIM * DIM, base + (size_t)2 * DIM * DIM, DIM, DIM);
    transpose_f32_bf16<<<dim3(DIM / 32, DIM / 32), tb32, 0, stream>>>(
        wo + (size_t)l * DIM * DIM, woT + (size_t)l * DIM * DIM, DIM, DIM);
    transpose_f32_bf16<<<dim3(FFN / 32, DIM / 32), tb32, 0, stream>>>(
        w1 + (size_t)l * DIM * FFN, w1T + (size_t)l * DIM * FFN, DIM, FFN);
    transpose_f32_bf16<<<dim3(DIM / 32, FFN / 32), tb32, 0, stream>>>(
        w2 + (size_t)l * DIM * FFN, w2T + (size_t)l * DIM * FFN, FFN, DIM);
    pack_qkv_bias<<<QKVN / 256, 256, 0, stream>>>(
        bq + (size_t)l * DIM, bk + (size_t)l * DIM, bv + (size_t)l * DIM,
        bqkv + (size_t)l * QKVN);
  }
  transpose_f32_bf16<<<dim3(VOCAB / 32, DIM / 32), tb32, 0, stream>>>(
      head_w, headT, DIM, VOCAB);

  embed_gather<<<ROWS, 256, 0, stream>>>(ids, emb, x);
  rmsnorm_kernel<<<ROWS, 256, 0, stream>>>(x, g1, h);

  for (int l = 0; l < LAYERS; l++) {
    gemm128_kernel<1, 0, 0, 1>
        <<<(ROWS / 128) * (QKVN / 128), 256, 0, stream>>>(
            h, wqkvT + (size_t)l * QKVN * DIM, bqkv + (size_t)l * QKVN,
            qkvb, nullptr, ROWS, QKVN, DIM);
    vtrans_kernel<<<dim3(SEQ / 64, BATCH * HEADS), 256, 0, stream>>>(qkvb, vtb);
    attn_kernel<<<dim3(SEQ / 64, BATCH * HEADS), 256, 0, stream>>>(qkvb, vtb, ob);
    gemm128_kernel<0, 0, 1, 0>
        <<<2 * (ROWS / 128) * (DIM / 128), 256, 0, stream>>>(
            ob, woT + (size_t)l * DIM * DIM, nullptr, P0, P1, ROWS, DIM, DIM);
    addnorm_kernel<<<ROWS, 256, 0, stream>>>(
        x, P0, P1, bo + (size_t)l * DIM, g2 + (size_t)l * DIM, h);
    gemm128_kernel<1, 1, 0, 1>
        <<<(ROWS / 128) * (FFN / 128), 256, 0, stream>>>(
            h, w1T + (size_t)l * DIM * FFN, b1 + (size_t)l * FFN, tb, nullptr,
            ROWS, FFN, DIM);
    gemm128_kernel<0, 0, 1, 0>
        <<<2 * (ROWS / 128) * (DIM / 128), 256, 0, stream>>>(
            tb, w2T + (size_t)l * DIM * FFN, nullptr, P0, P1, ROWS, DIM, FFN);
    addnorm_kernel<<<ROWS, 256, 0, stream>>>(
        x, P0, P1, b2 + (size_t)l * DIM,
        (l == LAYERS - 1) ? gf : (g1 + (size_t)(l + 1) * DIM), h);
  }
  gemm256p_kernel<<<(VOCAB / 256) * 2, 512, 0, stream>>>(
      h, headT, head_b, out, ROWS, VOCAB, DIM);
}